// Round 3
// baseline (1182.948 us; speedup 1.0000x reference)
//
#include <hip/hip_runtime.h>
#include <stdint.h>

// Problem: ConcatLayer_55654186221983 on MI355X (gfx950).
// B=8, C=128, C2=256, H=W=64, EMB=512, GROUPS=32 (4 ch/group), EPS=1e-5.
// All inputs fp32 (per reference setup_inputs dtype=jnp.float32), output fp32.
// Round 1/2 NaN root cause: inputs were read as bf16 — mantissa halves of
// fp32 words decode to NaN/Inf ~0.4% of the time. Everything fp32 now.

#define B_   8
#define C_   128
#define C2_  256
#define HW_  4096
#define EMB_ 512
#define EPS_ 1e-5f

__device__ __forceinline__ float ld_f(const float* p) { return *p; }
__device__ __forceinline__ float ld_f(const int8_t* p) { return (float)(*p); }
__device__ __forceinline__ float silu(float v) { return v / (1.f + expf(-v)); }

// ---------------- binary conv weights: bw = alpha_o * sign(w) ----------------
__global__ __launch_bounds__(256) void k_bw(const float* __restrict__ w,
                                            float* __restrict__ bw) {
    __shared__ float red[256];
    __shared__ float s_alpha;
    const int tid = threadIdx.x, o = blockIdx.x;
    const float* wr = w + (size_t)o * (C2_ * 9);
    float s = 0.f;
    for (int i = tid; i < C2_ * 9; i += 256) s += fabsf(wr[i]);
    red[tid] = s;
    __syncthreads();
    for (int st = 128; st > 0; st >>= 1) {
        if (tid < st) red[tid] += red[tid + st];
        __syncthreads();
    }
    if (tid == 0) s_alpha = red[0] / (float)(C2_ * 9);
    __syncthreads();
    const float a = s_alpha;
    for (int i = tid; i < C2_ * 9; i += 256) {
        float v = wr[i];
        bw[(size_t)o * (C2_ * 9) + i] = (v > 0.f) ? a : ((v < 0.f) ? -a : 0.f);
    }
}

// ---------------- embedding MLPs ----------------
// eo[8,256] (scale|shift), b1[8,256], b2[8,128], b3[8,128]
__global__ __launch_bounds__(256) void k_emb(
    const float* __restrict__ emb,
    const float* __restrict__ ew, const float* __restrict__ ebb,
    const float* __restrict__ m1w, const float* __restrict__ m1b,
    const float* __restrict__ m2w, const float* __restrict__ m2b,
    const float* __restrict__ m3w, const float* __restrict__ m3b,
    float* __restrict__ eo, float* __restrict__ b1,
    float* __restrict__ b2, float* __restrict__ b3) {
    __shared__ float se[EMB_];
    const int tid = threadIdx.x, bb = blockIdx.x;
    for (int i = tid; i < EMB_; i += 256) se[i] = silu(emb[bb * EMB_ + i]);
    __syncthreads();
    for (int o = tid; o < 768; o += 256) {
        const float* w;
        float bias;
        float* dst;
        if (o < 256)      { w = ew  + (size_t)o * EMB_;              bias = ebb[o];    dst = eo + bb * 256 + o; }
        else if (o < 512) { int r = o - 256; w = m1w + (size_t)r * EMB_; bias = m1b[r]; dst = b1 + bb * 256 + r; }
        else if (o < 640) { int r = o - 512; w = m2w + (size_t)r * EMB_; bias = m2b[r]; dst = b2 + bb * 128 + r; }
        else              { int r = o - 640; w = m3w + (size_t)r * EMB_; bias = m3b[r]; dst = b3 + bb * 128 + r; }
        float s = bias;
        for (int k = 0; k < EMB_; ++k) s += se[k] * w[k];
        *dst = s;
    }
}

// ---------------- GroupNorm (+SiLU), one block per (n,group) ----------------
__global__ __launch_bounds__(256) void k_gn1(const float* __restrict__ in,
                                             const float* __restrict__ g,
                                             const float* __restrict__ b,
                                             float* __restrict__ out) {
    __shared__ float ssum[256], ssq[256];
    __shared__ float s_mu, s_rstd;
    const int tid = threadIdx.x;
    const int n = blockIdx.x >> 5, grp = blockIdx.x & 31;
    const size_t base = ((size_t)(n * C_ + grp * 4)) << 12;
    float sum = 0.f, sq = 0.f;
    for (int i = tid; i < 16384; i += 256) {
        float v = in[base + i];
        sum += v; sq += v * v;
    }
    ssum[tid] = sum; ssq[tid] = sq;
    __syncthreads();
    for (int st = 128; st > 0; st >>= 1) {
        if (tid < st) { ssum[tid] += ssum[tid + st]; ssq[tid] += ssq[tid + st]; }
        __syncthreads();
    }
    if (tid == 0) {
        float mu = ssum[0] * (1.f / 16384.f);
        float var = ssq[0] * (1.f / 16384.f) - mu * mu;
        s_mu = mu; s_rstd = rsqrtf(var + EPS_);
    }
    __syncthreads();
    const float mu = s_mu, rstd = s_rstd;
    for (int i = tid; i < 16384; i += 256) {
        int ch = grp * 4 + (i >> 12);
        float v = in[base + i];
        float y = (v - mu) * rstd * g[ch] + b[ch];
        out[base + i] = silu(y);
    }
}

// GN2 + FiLM (scale/shift from eo) + SiLU
__global__ __launch_bounds__(256) void k_gn2(const float* __restrict__ in,
                                             const float* __restrict__ g,
                                             const float* __restrict__ b,
                                             const float* __restrict__ eo,
                                             float* __restrict__ out) {
    __shared__ float ssum[256], ssq[256];
    __shared__ float s_mu, s_rstd;
    const int tid = threadIdx.x;
    const int n = blockIdx.x >> 5, grp = blockIdx.x & 31;
    const size_t base = ((size_t)(n * C_ + grp * 4)) << 12;
    float sum = 0.f, sq = 0.f;
    for (int i = tid; i < 16384; i += 256) {
        float v = in[base + i];
        sum += v; sq += v * v;
    }
    ssum[tid] = sum; ssq[tid] = sq;
    __syncthreads();
    for (int st = 128; st > 0; st >>= 1) {
        if (tid < st) { ssum[tid] += ssum[tid + st]; ssq[tid] += ssq[tid + st]; }
        __syncthreads();
    }
    if (tid == 0) {
        float mu = ssum[0] * (1.f / 16384.f);
        float var = ssq[0] * (1.f / 16384.f) - mu * mu;
        s_mu = mu; s_rstd = rsqrtf(var + EPS_);
    }
    __syncthreads();
    const float mu = s_mu, rstd = s_rstd;
    for (int i = tid; i < 16384; i += 256) {
        int ch = grp * 4 + (i >> 12);
        float scale = eo[n * 256 + ch];
        float shift = eo[n * 256 + 128 + ch];
        float v = in[base + i];
        float y = (v - mu) * rstd * g[ch] + b[ch];
        y = y * (1.f + scale) + shift;
        out[base + i] = silu(y);
    }
}

// ---------------- direct 3x3 conv ----------------
// block: 16 out-channels x (16x16) pixel tile; grid (16 tiles, 8 co-tiles, 8 n)
template <int CIN, bool ADD_RES, typename Tin>
__global__ __launch_bounds__(256) void k_conv3x3(const Tin* __restrict__ in,
                                                 const float* __restrict__ wgt,
                                                 const float* __restrict__ bias,
                                                 const float* __restrict__ res,
                                                 float* __restrict__ out) {
    __shared__ float lin[18 * 18];
    const int tid = threadIdx.x;
    const int n = blockIdx.z;
    const int co_base = blockIdx.y * 16;
    const int tile = blockIdx.x;
    const int tx0 = (tile & 3) * 16, ty0 = (tile >> 2) * 16;
    const int px = tid & 15, py = tid >> 4;
    const int ox = tx0 + px, oy = ty0 + py;

    float acc[16];
#pragma unroll
    for (int i = 0; i < 16; ++i) acc[i] = 0.f;

    for (int ci = 0; ci < CIN; ++ci) {
        const Tin* inp = in + (((size_t)(n * CIN + ci)) << 12);
        for (int idx = tid; idx < 324; idx += 256) {
            int r = idx / 18;
            int iy = ty0 + r - 1;
            int ix = tx0 + (idx - r * 18) - 1;
            float v = 0.f;
            if (iy >= 0 && iy < 64 && ix >= 0 && ix < 64) v = ld_f(inp + (iy << 6) + ix);
            lin[idx] = v;
        }
        __syncthreads();
        float in9[9];
#pragma unroll
        for (int dy = 0; dy < 3; ++dy)
#pragma unroll
            for (int dx = 0; dx < 3; ++dx)
                in9[dy * 3 + dx] = lin[(py + dy) * 18 + (px + dx)];
        const float* wp = wgt + ((size_t)co_base * CIN + ci) * 9;
#pragma unroll
        for (int co = 0; co < 16; ++co) {
            const float* w9 = wp + (size_t)co * CIN * 9;
#pragma unroll
            for (int k = 0; k < 9; ++k) acc[co] += w9[k] * in9[k];
        }
        __syncthreads();
    }
#pragma unroll
    for (int co = 0; co < 16; ++co) {
        const int cog = co_base + co;
        const size_t oidx = (((size_t)(n * C_ + cog)) << 12) + (oy << 6) + ox;
        float v = acc[co] + bias[cog];
        if (ADD_RES) v += res[oidx];
        out[oidx] = v;
    }
}

// ---------------- sign (binarize concat + bias1) -> int8 ----------------
__global__ __launch_bounds__(256) void k_sign(const float* __restrict__ x,
                                              const float* __restrict__ c2,
                                              const float* __restrict__ b1,
                                              int8_t* __restrict__ s) {
    const int idx = blockIdx.x * 256 + threadIdx.x;  // < 8,388,608
    const int hw = idx & 4095;
    const int cb = idx >> 12;
    const int ch = cb & 255;
    const int n = cb >> 8;
    float v;
    if (ch < 128) v = x[(((size_t)(n * C_ + ch)) << 12) + hw];
    else          v = c2[(((size_t)(n * C_ + (ch - 128))) << 12) + hw];
    v += b1[n * 256 + ch];
    s[idx] = (v > 0.f) ? (int8_t)1 : ((v < 0.f) ? (int8_t)(-1) : (int8_t)0);
}

// ---------------- BatchNorm stats ----------------
__global__ __launch_bounds__(256) void k_bnstats(const float* __restrict__ y,
                                                 float* __restrict__ st) {
    __shared__ float ssum[256], ssq[256];
    const int tid = threadIdx.x, o = blockIdx.x;
    float s = 0.f, q = 0.f;
    for (int n = 0; n < B_; ++n) {
        const float* p = y + (((size_t)(n * C_ + o)) << 12);
        for (int i = tid; i < HW_; i += 256) {
            float v = p[i];
            s += v; q += v * v;
        }
    }
    ssum[tid] = s; ssq[tid] = q;
    __syncthreads();
    for (int st2 = 128; st2 > 0; st2 >>= 1) {
        if (tid < st2) { ssum[tid] += ssum[tid + st2]; ssq[tid] += ssq[tid + st2]; }
        __syncthreads();
    }
    if (tid == 0) {
        float mu = ssum[0] * (1.f / 32768.f);
        float var = ssq[0] * (1.f / 32768.f) - mu * mu;
        st[o] = mu;
        st[128 + o] = rsqrtf(var + EPS_);
    }
}

// ---------------- final epilogue ----------------
__global__ __launch_bounds__(256) void k_final(const float* __restrict__ y3,
                                               const float* __restrict__ x,
                                               const float* __restrict__ c2,
                                               const float* __restrict__ st,
                                               const float* __restrict__ bng,
                                               const float* __restrict__ bnb,
                                               const float* __restrict__ b2v,
                                               const float* __restrict__ pa,
                                               const float* __restrict__ b3v,
                                               float* __restrict__ out) {
    const int idx = blockIdx.x * 256 + threadIdx.x;  // < 4,194,304
    const int hw = idx & 4095;
    const int cb = idx >> 12;
    const int co = cb & 127;
    const int n = cb >> 7;
    float v = (y3[idx] - st[co]) * st[128 + co] * bng[co] + bnb[co];
    const int ch0 = 2 * co;
    float p;
    if (co < 64) {
        p = 0.5f * (x[(((size_t)(n * C_ + ch0)) << 12) + hw] +
                    x[(((size_t)(n * C_ + ch0 + 1)) << 12) + hw]);
    } else {
        int d = ch0 - 128;
        p = 0.5f * (c2[(((size_t)(n * C_ + d)) << 12) + hw] +
                    c2[(((size_t)(n * C_ + d + 1)) << 12) + hw]);
    }
    v += p + b2v[n * 128 + co];
    v = (v >= 0.f) ? v : pa[co] * v;
    v += b3v[n * 128 + co];
    out[idx] = v;
}

// ---------------- launch ----------------
extern "C" void kernel_launch(void* const* d_in, const int* in_sizes, int n_in,
                              void* d_out, int out_size, void* d_ws, size_t ws_size,
                              hipStream_t stream) {
    const float* c       = (const float*)d_in[0];
    const float* x       = (const float*)d_in[1];
    const float* emb     = (const float*)d_in[2];
    const float* gn1_g   = (const float*)d_in[3];
    const float* gn1_b   = (const float*)d_in[4];
    const float* conv1_w = (const float*)d_in[5];
    const float* conv1_b = (const float*)d_in[6];
    const float* emb_w   = (const float*)d_in[7];
    const float* emb_b   = (const float*)d_in[8];
    const float* gn2_g   = (const float*)d_in[9];
    const float* gn2_b   = (const float*)d_in[10];
    const float* conv2_w = (const float*)d_in[11];
    const float* conv2_b = (const float*)d_in[12];
    const float* m1_w    = (const float*)d_in[13];
    const float* m1_b    = (const float*)d_in[14];
    const float* bconv_w = (const float*)d_in[15];
    const float* bconv_b = (const float*)d_in[16];
    const float* bn_g    = (const float*)d_in[17];
    const float* bn_b    = (const float*)d_in[18];
    const float* m2_w    = (const float*)d_in[19];
    const float* m2_b    = (const float*)d_in[20];
    const float* prelu_a = (const float*)d_in[21];
    const float* m3_w    = (const float*)d_in[22];
    const float* m3_b    = (const float*)d_in[23];
    float* out = (float*)d_out;

    // Workspace layout (~41.2 MB):
    //   a_buf fp32 [4M]  16 MB   (a1 -> a2 -> y3)
    //   y_buf fp32 [4M]  16 MB   (y1 -> c2)
    //   s_buf int8 [8M]   8 MB   (binarized concat)
    //   bwf   fp32        1.2 MB (binary weights)
    //   small vectors     ~26 KB
    float* ws = (float*)d_ws;
    const size_t NCHW = (size_t)B_ * C_ * HW_;      // 4,194,304
    float*  a_buf = ws;
    float*  y_buf = ws + NCHW;
    int8_t* s_buf = (int8_t*)(ws + 2 * NCHW);        // 8M bytes = 2M floats
    float*  bwf   = ws + 2 * NCHW + (NCHW / 2);      // 294912
    float*  eo    = bwf + C_ * C2_ * 9;              // 2048
    float*  b1v   = eo + B_ * 256;                   // 2048
    float*  b2v   = b1v + B_ * 256;                  // 1024
    float*  b3v   = b2v + B_ * 128;                  // 1024
    float*  bnst  = b3v + B_ * 128;                  // 256

    // prep
    k_bw<<<C_, 256, 0, stream>>>(bconv_w, bwf);
    k_emb<<<B_, 256, 0, stream>>>(emb, emb_w, emb_b, m1_w, m1_b, m2_w, m2_b,
                                  m3_w, m3_b, eo, b1v, b2v, b3v);
    // ResBlock
    k_gn1<<<B_ * 32, 256, 0, stream>>>(c, gn1_g, gn1_b, a_buf);
    k_conv3x3<C_, false, float><<<dim3(16, 8, B_), 256, 0, stream>>>(a_buf, conv1_w, conv1_b, nullptr, y_buf);
    k_gn2<<<B_ * 32, 256, 0, stream>>>(y_buf, gn2_g, gn2_b, eo, a_buf);
    k_conv3x3<C_, true, float><<<dim3(16, 8, B_), 256, 0, stream>>>(a_buf, conv2_w, conv2_b, c, y_buf); // y_buf = c2
    // binarize + binary conv
    k_sign<<<(2 * NCHW) / 256, 256, 0, stream>>>(x, y_buf, b1v, s_buf);
    k_conv3x3<C2_, false, int8_t><<<dim3(16, 8, B_), 256, 0, stream>>>(s_buf, bwf, bconv_b, nullptr, a_buf); // a_buf = y3
    // batch norm + epilogue
    k_bnstats<<<C_, 256, 0, stream>>>(a_buf, bnst);
    k_final<<<NCHW / 256, 256, 0, stream>>>(a_buf, x, y_buf, bnst, bn_g, bn_b,
                                            b2v, prelu_a, b3v, out);
}

// Round 4
// 1115.118 us; speedup vs baseline: 1.0608x; 1.0608x over previous
//
#include <hip/hip_runtime.h>
#include <stdint.h>

// ConcatLayer_55654186221983 on MI355X (gfx950). All fp32 I/O.
// B=8, C=128, C2=256, H=W=64, EMB=512, GROUPS=32, EPS=1e-5.
// R4: binary conv -> exact i8 MFMA implicit GEMM (inputs/weights in {-1,0,1});
//     conv1/conv2 -> chunked-LDS direct conv, FMA-bound.

#define B_   8
#define C_   128
#define C2_  256
#define HW_  4096
#define EMB_ 512
#define EPS_ 1e-5f

typedef int v16i __attribute__((ext_vector_type(16)));

__device__ __forceinline__ float silu(float v) { return v / (1.f + expf(-v)); }

// ---------------- binary weight prep: sgn[9][128][256] int8 + alpha[128] ----
__global__ __launch_bounds__(256) void k_bw(const float* __restrict__ w,
                                            int8_t* __restrict__ sgn,
                                            float* __restrict__ alpha) {
    __shared__ float red[256];
    const int tid = threadIdx.x, o = blockIdx.x;
    const float* wr = w + (size_t)o * (C2_ * 9);
    float s = 0.f;
    for (int i = tid; i < C2_ * 9; i += 256) s += fabsf(wr[i]);
    red[tid] = s;
    __syncthreads();
    for (int st = 128; st > 0; st >>= 1) {
        if (tid < st) red[tid] += red[tid + st];
        __syncthreads();
    }
    if (tid == 0) alpha[o] = red[0] / (float)(C2_ * 9);
    for (int kk = 0; kk < 9; ++kk) {
        float v = wr[tid * 9 + kk];   // tid == ci (256 threads)
        sgn[((size_t)kk * C_ + o) * C2_ + tid] =
            (v > 0.f) ? (int8_t)1 : ((v < 0.f) ? (int8_t)(-1) : (int8_t)0);
    }
}

// ---------------- embedding MLPs ----------------
__global__ __launch_bounds__(256) void k_emb(
    const float* __restrict__ emb,
    const float* __restrict__ ew, const float* __restrict__ ebb,
    const float* __restrict__ m1w, const float* __restrict__ m1b,
    const float* __restrict__ m2w, const float* __restrict__ m2b,
    const float* __restrict__ m3w, const float* __restrict__ m3b,
    float* __restrict__ eo, float* __restrict__ b1,
    float* __restrict__ b2, float* __restrict__ b3) {
    __shared__ float se[EMB_];
    const int tid = threadIdx.x, bb = blockIdx.x;
    for (int i = tid; i < EMB_; i += 256) se[i] = silu(emb[bb * EMB_ + i]);
    __syncthreads();
    for (int o = tid; o < 768; o += 256) {
        const float* w;
        float bias;
        float* dst;
        if (o < 256)      { w = ew  + (size_t)o * EMB_;              bias = ebb[o];    dst = eo + bb * 256 + o; }
        else if (o < 512) { int r = o - 256; w = m1w + (size_t)r * EMB_; bias = m1b[r]; dst = b1 + bb * 256 + r; }
        else if (o < 640) { int r = o - 512; w = m2w + (size_t)r * EMB_; bias = m2b[r]; dst = b2 + bb * 128 + r; }
        else              { int r = o - 640; w = m3w + (size_t)r * EMB_; bias = m3b[r]; dst = b3 + bb * 128 + r; }
        float s = bias;
        for (int k = 0; k < EMB_; ++k) s += se[k] * w[k];
        *dst = s;
    }
}

// ---------------- GroupNorm (+SiLU) ----------------
__global__ __launch_bounds__(256) void k_gn1(const float* __restrict__ in,
                                             const float* __restrict__ g,
                                             const float* __restrict__ b,
                                             float* __restrict__ out) {
    __shared__ float ssum[256], ssq[256];
    __shared__ float s_mu, s_rstd;
    const int tid = threadIdx.x;
    const int n = blockIdx.x >> 5, grp = blockIdx.x & 31;
    const size_t base = ((size_t)(n * C_ + grp * 4)) << 12;
    float sum = 0.f, sq = 0.f;
    for (int i = tid; i < 16384; i += 256) {
        float v = in[base + i];
        sum += v; sq += v * v;
    }
    ssum[tid] = sum; ssq[tid] = sq;
    __syncthreads();
    for (int st = 128; st > 0; st >>= 1) {
        if (tid < st) { ssum[tid] += ssum[tid + st]; ssq[tid] += ssq[tid + st]; }
        __syncthreads();
    }
    if (tid == 0) {
        float mu = ssum[0] * (1.f / 16384.f);
        float var = ssq[0] * (1.f / 16384.f) - mu * mu;
        s_mu = mu; s_rstd = rsqrtf(var + EPS_);
    }
    __syncthreads();
    const float mu = s_mu, rstd = s_rstd;
    for (int i = tid; i < 16384; i += 256) {
        int ch = grp * 4 + (i >> 12);
        float v = in[base + i];
        out[base + i] = silu((v - mu) * rstd * g[ch] + b[ch]);
    }
}

__global__ __launch_bounds__(256) void k_gn2(const float* __restrict__ in,
                                             const float* __restrict__ g,
                                             const float* __restrict__ b,
                                             const float* __restrict__ eo,
                                             float* __restrict__ out) {
    __shared__ float ssum[256], ssq[256];
    __shared__ float s_mu, s_rstd;
    const int tid = threadIdx.x;
    const int n = blockIdx.x >> 5, grp = blockIdx.x & 31;
    const size_t base = ((size_t)(n * C_ + grp * 4)) << 12;
    float sum = 0.f, sq = 0.f;
    for (int i = tid; i < 16384; i += 256) {
        float v = in[base + i];
        sum += v; sq += v * v;
    }
    ssum[tid] = sum; ssq[tid] = sq;
    __syncthreads();
    for (int st = 128; st > 0; st >>= 1) {
        if (tid < st) { ssum[tid] += ssum[tid + st]; ssq[tid] += ssq[tid + st]; }
        __syncthreads();
    }
    if (tid == 0) {
        float mu = ssum[0] * (1.f / 16384.f);
        float var = ssq[0] * (1.f / 16384.f) - mu * mu;
        s_mu = mu; s_rstd = rsqrtf(var + EPS_);
    }
    __syncthreads();
    const float mu = s_mu, rstd = s_rstd;
    for (int i = tid; i < 16384; i += 256) {
        int ch = grp * 4 + (i >> 12);
        float v = in[base + i];
        float y = (v - mu) * rstd * g[ch] + b[ch];
        y = y * (1.f + eo[n * 256 + ch]) + eo[n * 256 + 128 + ch];
        out[base + i] = silu(y);
    }
}

// ---------------- fp32 3x3 conv, chunked LDS ----------------
// tile: 16co x 32x32 px; 256 thr; thread: 4co x 4x4 px; ci chunks of 8.
template <bool ADD_RES>
__global__ __launch_bounds__(256) void k_conv3s(const float* __restrict__ in,
                                                const float* __restrict__ wgt,
                                                const float* __restrict__ bias,
                                                const float* __restrict__ res,
                                                float* __restrict__ out) {
    __shared__ float lin[8][34 * 34];
    __shared__ float lw[8][16][10];
    const int tid = threadIdx.x;
    const int n = blockIdx.z, cot = blockIdx.y, pxt = blockIdx.x;
    const int x0 = 32 * (pxt & 1), y0 = 32 * (pxt >> 1);
    const int co0 = cot * 16;
    const int cid = tid >> 6;            // 0..3
    const int pid = tid & 63;
    const int tx = 4 * (pid & 7), ty = 4 * (pid >> 3);

    float acc[4][16];
#pragma unroll
    for (int j = 0; j < 4; ++j)
#pragma unroll
        for (int p = 0; p < 16; ++p) acc[j][p] = 0.f;

    for (int cc = 0; cc < C_; cc += 8) {
        for (int idx = tid; idx < 8 * 1156; idx += 256) {
            int ci = idx / 1156, r = idx - ci * 1156;
            int ry = r / 34, rx = r - ry * 34;
            int gy = y0 + ry - 1, gx = x0 + rx - 1;
            float v = 0.f;
            if (gy >= 0 && gy < 64 && gx >= 0 && gx < 64)
                v = in[((size_t)(n * C_ + cc + ci) << 12) + (gy << 6) + gx];
            lin[ci][r] = v;
        }
        for (int idx = tid; idx < 8 * 16 * 9; idx += 256) {
            int ci = idx / 144, rem = idx - ci * 144, co = rem / 9, k = rem - co * 9;
            lw[ci][co][k] = wgt[((size_t)(co0 + co) * C_ + cc + ci) * 9 + k];
        }
        __syncthreads();
#pragma unroll 2
        for (int ci = 0; ci < 8; ++ci) {
            float win[6][6];
#pragma unroll
            for (int r = 0; r < 6; ++r)
#pragma unroll
                for (int c = 0; c < 6; ++c)
                    win[r][c] = lin[ci][(ty + r) * 34 + tx + c];
#pragma unroll
            for (int j = 0; j < 4; ++j) {
                float w9[9];
#pragma unroll
                for (int k = 0; k < 9; ++k) w9[k] = lw[ci][4 * cid + j][k];
#pragma unroll
                for (int py = 0; py < 4; ++py)
#pragma unroll
                    for (int px = 0; px < 4; ++px) {
                        float a = acc[j][py * 4 + px];
#pragma unroll
                        for (int ky = 0; ky < 3; ++ky)
#pragma unroll
                            for (int kx = 0; kx < 3; ++kx)
                                a += w9[ky * 3 + kx] * win[py + ky][px + kx];
                        acc[j][py * 4 + px] = a;
                    }
            }
        }
        __syncthreads();
    }
#pragma unroll
    for (int j = 0; j < 4; ++j) {
        const int co = co0 + 4 * cid + j;
        const float bv = bias[co];
        const size_t base = ((size_t)(n * C_ + co)) << 12;
#pragma unroll
        for (int py = 0; py < 4; ++py)
#pragma unroll
            for (int px = 0; px < 4; ++px) {
                const size_t o = base + ((y0 + ty + py) << 6) + x0 + tx + px;
                float v = acc[j][py * 4 + px] + bv;
                if (ADD_RES) v += res[o];
                out[o] = v;
            }
    }
}

// ---------------- sign + transpose: S[n][hw][256] int8 ----------------
__global__ __launch_bounds__(256) void k_sign_t(const float* __restrict__ x,
                                                const float* __restrict__ c2,
                                                const float* __restrict__ b1,
                                                int8_t* __restrict__ S) {
    __shared__ int lds[64 * 65];
    const int t = threadIdx.x;
    const int hw0 = blockIdx.x * 64, n = blockIdx.y;
    const int hwo = t & 63, chq0 = t >> 6;
    for (int it = 0; it < 16; ++it) {
        int chq = it * 4 + chq0;          // 0..63 -> ch = 4*chq + j
        int pk = 0;
#pragma unroll
        for (int j = 0; j < 4; ++j) {
            int ch = 4 * chq + j;
            float v = (ch < 128) ? x[((size_t)(n * C_ + ch) << 12) + hw0 + hwo]
                                 : c2[((size_t)(n * C_ + ch - 128) << 12) + hw0 + hwo];
            v += b1[n * 256 + ch];
            int sg = (v > 0.f) ? 1 : ((v < 0.f) ? -1 : 0);
            pk |= (sg & 0xFF) << (8 * j);
        }
        lds[hwo * 65 + chq] = pk;
    }
    __syncthreads();
    int* So = (int*)S;
    for (int p = 0; p < 16; ++p) {
        int idx = p * 256 + t;
        int pl = idx >> 6, cq = idx & 63;
        So[((size_t)(n * HW_ + hw0 + pl)) * 64 + cq] = lds[pl * 65 + cq];
    }
}

// ---------------- binary conv: i8 MFMA implicit GEMM ----------------
// block: (n, y); 4 waves; wave w -> co [32w,32w+32), two 32-px x-tiles.
__global__ __launch_bounds__(256) void k_bconv(const int8_t* __restrict__ S,
                                               const int8_t* __restrict__ Wk,
                                               const float* __restrict__ alpha,
                                               const float* __restrict__ bias,
                                               float* __restrict__ out) {
    const int y = blockIdx.x;
    const int n = blockIdx.y;
    const int w = threadIdx.x >> 6;
    const int l = threadIdx.x & 63;
    const int lm = l & 31;
    const int lh = l >> 5;

    v16i acc0, acc1;
#pragma unroll
    for (int i = 0; i < 16; ++i) { acc0[i] = 0; acc1[i] = 0; }

    for (int kk = 0; kk < 9; ++kk) {
        const int dy = kk / 3 - 1, dx = kk % 3 - 1;
        const int yy = y + dy;
        if (yy < 0 || yy > 63) continue;
        const int8_t* wrow = Wk + ((size_t)kk * C_ + 32 * w + lm) * C2_ + 8 * lh;
        const size_t prow = (((size_t)n * 64 + yy) * 64) * (size_t)C2_;
        const int x0 = lm + dx;        // tile 0: in [-1, 32]
        const int x1 = 32 + lm + dx;   // tile 1: in [31, 64]
#pragma unroll
        for (int s = 0; s < 16; ++s) {
            long a = *(const long*)(wrow + 16 * s);
            long b0 = 0, b1 = 0;
            if (x0 >= 0) b0 = *(const long*)(S + prow + (size_t)(x0 * 256 + 16 * s + 8 * lh));
            if (x1 <= 63) b1 = *(const long*)(S + prow + (size_t)(x1 * 256 + 16 * s + 8 * lh));
            acc0 = __builtin_amdgcn_mfma_i32_32x32x16_i8(a, b0, acc0, 0, 0, 0);
            acc1 = __builtin_amdgcn_mfma_i32_32x32x16_i8(a, b1, acc1, 0, 0, 0);
        }
    }
#pragma unroll
    for (int r = 0; r < 16; ++r) {
        const int row = (r & 3) + 8 * (r >> 2) + 4 * lh;
        const int co = 32 * w + row;
        const float av = alpha[co], bv = bias[co];
        const size_t o = (((size_t)n * C_ + co) << 12) + (y << 6);
        out[o + lm]      = av * (float)acc0[r] + bv;
        out[o + 32 + lm] = av * (float)acc1[r] + bv;
    }
}

// ---------------- BatchNorm stats ----------------
__global__ __launch_bounds__(256) void k_bnstats(const float* __restrict__ y,
                                                 float* __restrict__ st) {
    __shared__ float ssum[256], ssq[256];
    const int tid = threadIdx.x, o = blockIdx.x;
    float s = 0.f, q = 0.f;
    for (int n = 0; n < B_; ++n) {
        const float* p = y + (((size_t)(n * C_ + o)) << 12);
        for (int i = tid; i < HW_; i += 256) {
            float v = p[i];
            s += v; q += v * v;
        }
    }
    ssum[tid] = s; ssq[tid] = q;
    __syncthreads();
    for (int st2 = 128; st2 > 0; st2 >>= 1) {
        if (tid < st2) { ssum[tid] += ssum[tid + st2]; ssq[tid] += ssq[tid + st2]; }
        __syncthreads();
    }
    if (tid == 0) {
        float mu = ssum[0] * (1.f / 32768.f);
        float var = ssq[0] * (1.f / 32768.f) - mu * mu;
        st[o] = mu;
        st[128 + o] = rsqrtf(var + EPS_);
    }
}

// ---------------- final epilogue ----------------
__global__ __launch_bounds__(256) void k_final(const float* __restrict__ y3,
                                               const float* __restrict__ x,
                                               const float* __restrict__ c2,
                                               const float* __restrict__ st,
                                               const float* __restrict__ bng,
                                               const float* __restrict__ bnb,
                                               const float* __restrict__ b2v,
                                               const float* __restrict__ pa,
                                               const float* __restrict__ b3v,
                                               float* __restrict__ out) {
    const int idx = blockIdx.x * 256 + threadIdx.x;
    const int hw = idx & 4095;
    const int cb = idx >> 12;
    const int co = cb & 127;
    const int n = cb >> 7;
    float v = (y3[idx] - st[co]) * st[128 + co] * bng[co] + bnb[co];
    const int ch0 = 2 * co;
    float p;
    if (co < 64) {
        p = 0.5f * (x[(((size_t)(n * C_ + ch0)) << 12) + hw] +
                    x[(((size_t)(n * C_ + ch0 + 1)) << 12) + hw]);
    } else {
        int d = ch0 - 128;
        p = 0.5f * (c2[(((size_t)(n * C_ + d)) << 12) + hw] +
                    c2[(((size_t)(n * C_ + d + 1)) << 12) + hw]);
    }
    v += p + b2v[n * 128 + co];
    v = (v >= 0.f) ? v : pa[co] * v;
    v += b3v[n * 128 + co];
    out[idx] = v;
}

// ---------------- launch ----------------
extern "C" void kernel_launch(void* const* d_in, const int* in_sizes, int n_in,
                              void* d_out, int out_size, void* d_ws, size_t ws_size,
                              hipStream_t stream) {
    const float* c       = (const float*)d_in[0];
    const float* x       = (const float*)d_in[1];
    const float* emb     = (const float*)d_in[2];
    const float* gn1_g   = (const float*)d_in[3];
    const float* gn1_b   = (const float*)d_in[4];
    const float* conv1_w = (const float*)d_in[5];
    const float* conv1_b = (const float*)d_in[6];
    const float* emb_w   = (const float*)d_in[7];
    const float* emb_b   = (const float*)d_in[8];
    const float* gn2_g   = (const float*)d_in[9];
    const float* gn2_b   = (const float*)d_in[10];
    const float* conv2_w = (const float*)d_in[11];
    const float* conv2_b = (const float*)d_in[12];
    const float* m1_w    = (const float*)d_in[13];
    const float* m1_b    = (const float*)d_in[14];
    const float* bconv_w = (const float*)d_in[15];
    const float* bconv_b = (const float*)d_in[16];
    const float* bn_g    = (const float*)d_in[17];
    const float* bn_b    = (const float*)d_in[18];
    const float* m2_w    = (const float*)d_in[19];
    const float* m2_b    = (const float*)d_in[20];
    const float* prelu_a = (const float*)d_in[21];
    const float* m3_w    = (const float*)d_in[22];
    const float* m3_b    = (const float*)d_in[23];
    float* out = (float*)d_out;

    // ws: a_buf 16MB | y_buf 16MB | S 8MB | sgn 288KB | alpha+vecs ~26KB  (~40.6MB)
    float* ws = (float*)d_ws;
    const size_t NCHW = (size_t)B_ * C_ * HW_;       // 4,194,304
    float*  a_buf = ws;
    float*  y_buf = ws + NCHW;
    int8_t* S     = (int8_t*)(ws + 2 * NCHW);        // 8 MB
    int8_t* sgn   = (int8_t*)(ws + 2 * NCHW + NCHW / 2);  // 294912 B = 73728 floats
    float*  alpha = ws + 2 * NCHW + NCHW / 2 + 73728;
    float*  eo    = alpha + 128;
    float*  b1v   = eo + B_ * 256;
    float*  b2v   = b1v + B_ * 256;
    float*  b3v   = b2v + B_ * 128;
    float*  bnst  = b3v + B_ * 128;

    k_bw<<<C_, 256, 0, stream>>>(bconv_w, sgn, alpha);
    k_emb<<<B_, 256, 0, stream>>>(emb, emb_w, emb_b, m1_w, m1_b, m2_w, m2_b,
                                  m3_w, m3_b, eo, b1v, b2v, b3v);
    k_gn1<<<B_ * 32, 256, 0, stream>>>(c, gn1_g, gn1_b, a_buf);
    k_conv3s<false><<<dim3(4, 8, B_), 256, 0, stream>>>(a_buf, conv1_w, conv1_b, nullptr, y_buf);
    k_gn2<<<B_ * 32, 256, 0, stream>>>(y_buf, gn2_g, gn2_b, eo, a_buf);
    k_conv3s<true><<<dim3(4, 8, B_), 256, 0, stream>>>(a_buf, conv2_w, conv2_b, c, y_buf); // y_buf = c2
    k_sign_t<<<dim3(64, B_), 256, 0, stream>>>(x, y_buf, b1v, S);
    k_bconv<<<dim3(64, B_), 256, 0, stream>>>(S, sgn, alpha, bconv_b, a_buf);  // a_buf = y3
    k_bnstats<<<C_, 256, 0, stream>>>(a_buf, bnst);
    k_final<<<NCHW / 256, 256, 0, stream>>>(a_buf, x, y_buf, bnst, bn_g, bn_b,
                                            b2v, prelu_a, b3v, out);
}

// Round 5
// 473.882 us; speedup vs baseline: 2.4963x; 2.3532x over previous
//
#include <hip/hip_runtime.h>
#include <stdint.h>

// ConcatLayer_55654186221983 on MI355X (gfx950). All fp32 I/O.
// B=8, C=128, C2=256, H=W=64, EMB=512, GROUPS=32, EPS=1e-5.
// R5: conv1/conv2 -> bf16 MFMA implicit GEMM (same verified 32x32x16 operand
// layout as the i8 bconv); GN writes bf16 NHWC; BN stats via atomics.

#define B_   8
#define C_   128
#define C2_  256
#define HW_  4096
#define EMB_ 512
#define EPS_ 1e-5f

typedef int   v16i __attribute__((ext_vector_type(16)));
typedef float v16f __attribute__((ext_vector_type(16)));
typedef short v8s  __attribute__((ext_vector_type(8)));

__device__ __forceinline__ float silu(float v) { return v / (1.f + expf(-v)); }
__device__ __forceinline__ unsigned short f2bf(float f) {
    unsigned int x = __float_as_uint(f);
    return (unsigned short)((x + 0x7FFFu + ((x >> 16) & 1u)) >> 16);  // RNE
}

// ---- binary weight prep: sgn[9][128][256] i8 + alpha[128]; zero BN sums ----
__global__ __launch_bounds__(256) void k_bw(const float* __restrict__ w,
                                            int8_t* __restrict__ sgn,
                                            float* __restrict__ alpha,
                                            float* __restrict__ bnS,
                                            float* __restrict__ bnQ) {
    __shared__ float red[256];
    const int tid = threadIdx.x, o = blockIdx.x;
    if (o == 0) { bnS[tid & 127] = 0.f; bnQ[tid & 127] = 0.f; }
    const float* wr = w + (size_t)o * (C2_ * 9);
    float s = 0.f;
    for (int i = tid; i < C2_ * 9; i += 256) s += fabsf(wr[i]);
    red[tid] = s;
    __syncthreads();
    for (int st = 128; st > 0; st >>= 1) {
        if (tid < st) red[tid] += red[tid + st];
        __syncthreads();
    }
    if (tid == 0) alpha[o] = red[0] / (float)(C2_ * 9);
    for (int kk = 0; kk < 9; ++kk) {
        float v = wr[tid * 9 + kk];   // tid == ci
        sgn[((size_t)kk * C_ + o) * C2_ + tid] =
            (v > 0.f) ? (int8_t)1 : ((v < 0.f) ? (int8_t)(-1) : (int8_t)0);
    }
}

// ---- conv weight prep: [co][ci][3][3] fp32 -> [kk][co][ci] bf16, both convs ----
__global__ __launch_bounds__(256) void k_wprep(const float* __restrict__ w1,
                                               const float* __restrict__ w2,
                                               unsigned short* __restrict__ Wc1,
                                               unsigned short* __restrict__ Wc2) {
    int i = blockIdx.x * 256 + threadIdx.x;
    if (i >= C_ * C_ * 9) return;
    int co = i / (C_ * 9);
    int rem = i - co * (C_ * 9);
    int ci = rem / 9, kk = rem - ci * 9;
    size_t d = ((size_t)kk * C_ + co) * C_ + ci;
    Wc1[d] = f2bf(w1[i]);
    Wc2[d] = f2bf(w2[i]);
}

// ---------------- embedding MLPs ----------------
__global__ __launch_bounds__(256) void k_emb(
    const float* __restrict__ emb,
    const float* __restrict__ ew, const float* __restrict__ ebb,
    const float* __restrict__ m1w, const float* __restrict__ m1b,
    const float* __restrict__ m2w, const float* __restrict__ m2b,
    const float* __restrict__ m3w, const float* __restrict__ m3b,
    float* __restrict__ eo, float* __restrict__ b1,
    float* __restrict__ b2, float* __restrict__ b3) {
    __shared__ float se[EMB_];
    const int tid = threadIdx.x, bb = blockIdx.x;
    for (int i = tid; i < EMB_; i += 256) se[i] = silu(emb[bb * EMB_ + i]);
    __syncthreads();
    for (int o = tid; o < 768; o += 256) {
        const float* w;
        float bias;
        float* dst;
        if (o < 256)      { w = ew  + (size_t)o * EMB_;              bias = ebb[o];    dst = eo + bb * 256 + o; }
        else if (o < 512) { int r = o - 256; w = m1w + (size_t)r * EMB_; bias = m1b[r]; dst = b1 + bb * 256 + r; }
        else if (o < 640) { int r = o - 512; w = m2w + (size_t)r * EMB_; bias = m2b[r]; dst = b2 + bb * 128 + r; }
        else              { int r = o - 640; w = m3w + (size_t)r * EMB_; bias = m3b[r]; dst = b3 + bb * 128 + r; }
        float s = bias;
        for (int k = 0; k < EMB_; ++k) s += se[k] * w[k];
        *dst = s;
    }
}

// ---- GN1 + SiLU: NCHW fp32 in -> NHWC bf16 out (packed 4ch / 8B stores) ----
__global__ __launch_bounds__(256) void k_gn1t(const float* __restrict__ in,
                                              const float* __restrict__ g,
                                              const float* __restrict__ b,
                                              unsigned short* __restrict__ act) {
    __shared__ float ssum[256], ssq[256];
    __shared__ float s_mu, s_rstd;
    const int tid = threadIdx.x;
    const int n = blockIdx.x >> 5, grp = blockIdx.x & 31;
    const size_t base = ((size_t)(n * C_ + grp * 4)) << 12;
    float sum = 0.f, sq = 0.f;
    for (int i = tid; i < 16384; i += 256) {
        float v = in[base + i];
        sum += v; sq += v * v;
    }
    ssum[tid] = sum; ssq[tid] = sq;
    __syncthreads();
    for (int st = 128; st > 0; st >>= 1) {
        if (tid < st) { ssum[tid] += ssum[tid + st]; ssq[tid] += ssq[tid + st]; }
        __syncthreads();
    }
    if (tid == 0) {
        float mu = ssum[0] * (1.f / 16384.f);
        float var = ssq[0] * (1.f / 16384.f) - mu * mu;
        s_mu = mu; s_rstd = rsqrtf(var + EPS_);
    }
    __syncthreads();
    const float mu = s_mu, rstd = s_rstd;
    float gg[4], bb[4];
#pragma unroll
    for (int j = 0; j < 4; ++j) { gg[j] = g[grp * 4 + j]; bb[j] = b[grp * 4 + j]; }
    for (int hw = tid; hw < HW_; hw += 256) {
        union { unsigned short u[4]; uint2 v; } pk;
#pragma unroll
        for (int j = 0; j < 4; ++j) {
            float v = in[base + ((size_t)j << 12) + hw];
            pk.u[j] = f2bf(silu((v - mu) * rstd * gg[j] + bb[j]));
        }
        *(uint2*)(act + ((size_t)(n * HW_ + hw)) * C_ + grp * 4) = pk.v;
    }
}

// ---- GN2 + FiLM + SiLU: NCHW fp32 in -> NHWC bf16 out ----
__global__ __launch_bounds__(256) void k_gn2t(const float* __restrict__ in,
                                              const float* __restrict__ g,
                                              const float* __restrict__ b,
                                              const float* __restrict__ eo,
                                              unsigned short* __restrict__ act) {
    __shared__ float ssum[256], ssq[256];
    __shared__ float s_mu, s_rstd;
    const int tid = threadIdx.x;
    const int n = blockIdx.x >> 5, grp = blockIdx.x & 31;
    const size_t base = ((size_t)(n * C_ + grp * 4)) << 12;
    float sum = 0.f, sq = 0.f;
    for (int i = tid; i < 16384; i += 256) {
        float v = in[base + i];
        sum += v; sq += v * v;
    }
    ssum[tid] = sum; ssq[tid] = sq;
    __syncthreads();
    for (int st = 128; st > 0; st >>= 1) {
        if (tid < st) { ssum[tid] += ssum[tid + st]; ssq[tid] += ssq[tid + st]; }
        __syncthreads();
    }
    if (tid == 0) {
        float mu = ssum[0] * (1.f / 16384.f);
        float var = ssq[0] * (1.f / 16384.f) - mu * mu;
        s_mu = mu; s_rstd = rsqrtf(var + EPS_);
    }
    __syncthreads();
    const float mu = s_mu, rstd = s_rstd;
    float sc[4], sh[4], gg[4], bb[4];
#pragma unroll
    for (int j = 0; j < 4; ++j) {
        int ch = grp * 4 + j;
        gg[j] = g[ch]; bb[j] = b[ch];
        sc[j] = 1.f + eo[n * 256 + ch];
        sh[j] = eo[n * 256 + 128 + ch];
    }
    for (int hw = tid; hw < HW_; hw += 256) {
        union { unsigned short u[4]; uint2 v; } pk;
#pragma unroll
        for (int j = 0; j < 4; ++j) {
            float v = in[base + ((size_t)j << 12) + hw];
            float y = ((v - mu) * rstd * gg[j] + bb[j]) * sc[j] + sh[j];
            pk.u[j] = f2bf(silu(y));
        }
        *(uint2*)(act + ((size_t)(n * HW_ + hw)) * C_ + grp * 4) = pk.v;
    }
}

// ---- fp32-acc bf16 MFMA implicit-GEMM 3x3 conv ----
// block (y, n); 4 waves; wave w -> co [32w,32w+32); two 32-px x-tiles.
// act: [n][y][x][ci] bf16 (ushort), Wc: [kk][co][ci] bf16.
template <bool ADD_RES>
__global__ __launch_bounds__(256) void k_convm(const unsigned short* __restrict__ act,
                                               const unsigned short* __restrict__ Wc,
                                               const float* __restrict__ bias,
                                               const float* __restrict__ res,
                                               float* __restrict__ out) {
    const int y = blockIdx.x;
    const int n = blockIdx.y;
    const int w = threadIdx.x >> 6;
    const int l = threadIdx.x & 63;
    const int lm = l & 31;
    const int lh = l >> 5;

    v16f acc0, acc1;
#pragma unroll
    for (int i = 0; i < 16; ++i) { acc0[i] = 0.f; acc1[i] = 0.f; }

    for (int kk = 0; kk < 9; ++kk) {
        const int dy = kk / 3 - 1, dx = kk % 3 - 1;
        const int yy = y + dy;
        if (yy < 0 || yy > 63) continue;
        const unsigned short* wrow = Wc + ((size_t)kk * C_ + 32 * w + lm) * C_ + 8 * lh;
        const unsigned short* arow = act + ((size_t)(n * 64 + yy) * 64) * C_ + 8 * lh;
        const int x0 = lm + dx;         // [-1, 32]
        const int x1 = 32 + lm + dx;    // [31, 64]
#pragma unroll
        for (int cb = 0; cb < 8; ++cb) {
            v8s a = *(const v8s*)(wrow + 16 * cb);
            v8s b0 = {0, 0, 0, 0, 0, 0, 0, 0}, b1 = {0, 0, 0, 0, 0, 0, 0, 0};
            if (x0 >= 0) b0 = *(const v8s*)(arow + (size_t)x0 * C_ + 16 * cb);
            if (x1 <= 63) b1 = *(const v8s*)(arow + (size_t)x1 * C_ + 16 * cb);
            acc0 = __builtin_amdgcn_mfma_f32_32x32x16_bf16(a, b0, acc0, 0, 0, 0);
            acc1 = __builtin_amdgcn_mfma_f32_32x32x16_bf16(a, b1, acc1, 0, 0, 0);
        }
    }
#pragma unroll
    for (int r = 0; r < 16; ++r) {
        const int row = (r & 3) + 8 * (r >> 2) + 4 * lh;
        const int co = 32 * w + row;
        const float bv = bias[co];
        const size_t o = (((size_t)n * C_ + co) << 12) + (y << 6);
        float v0 = acc0[r] + bv, v1 = acc1[r] + bv;
        if (ADD_RES) { v0 += res[o + lm]; v1 += res[o + 32 + lm]; }
        out[o + lm] = v0;
        out[o + 32 + lm] = v1;
    }
}

// ---- sign + transpose: S[n][hw][256] int8 ----
__global__ __launch_bounds__(256) void k_sign_t(const float* __restrict__ x,
                                                const float* __restrict__ c2,
                                                const float* __restrict__ b1,
                                                int8_t* __restrict__ S) {
    __shared__ int lds[64 * 65];
    const int t = threadIdx.x;
    const int hw0 = blockIdx.x * 64, n = blockIdx.y;
    const int hwo = t & 63, chq0 = t >> 6;
    for (int it = 0; it < 16; ++it) {
        int chq = it * 4 + chq0;
        int pk = 0;
#pragma unroll
        for (int j = 0; j < 4; ++j) {
            int ch = 4 * chq + j;
            float v = (ch < 128) ? x[((size_t)(n * C_ + ch) << 12) + hw0 + hwo]
                                 : c2[((size_t)(n * C_ + ch - 128) << 12) + hw0 + hwo];
            v += b1[n * 256 + ch];
            int sg = (v > 0.f) ? 1 : ((v < 0.f) ? -1 : 0);
            pk |= (sg & 0xFF) << (8 * j);
        }
        lds[hwo * 65 + chq] = pk;
    }
    __syncthreads();
    int* So = (int*)S;
    for (int p = 0; p < 16; ++p) {
        int idx = p * 256 + t;
        int pl = idx >> 6, cq = idx & 63;
        So[((size_t)(n * HW_ + hw0 + pl)) * 64 + cq] = lds[pl * 65 + cq];
    }
}

// ---- binary conv: i8 MFMA implicit GEMM ----
__global__ __launch_bounds__(256) void k_bconv(const int8_t* __restrict__ S,
                                               const int8_t* __restrict__ Wk,
                                               const float* __restrict__ alpha,
                                               const float* __restrict__ bias,
                                               float* __restrict__ out) {
    const int y = blockIdx.x;
    const int n = blockIdx.y;
    const int w = threadIdx.x >> 6;
    const int l = threadIdx.x & 63;
    const int lm = l & 31;
    const int lh = l >> 5;

    v16i acc0, acc1;
#pragma unroll
    for (int i = 0; i < 16; ++i) { acc0[i] = 0; acc1[i] = 0; }

    for (int kk = 0; kk < 9; ++kk) {
        const int dy = kk / 3 - 1, dx = kk % 3 - 1;
        const int yy = y + dy;
        if (yy < 0 || yy > 63) continue;
        const int8_t* wrow = Wk + ((size_t)kk * C_ + 32 * w + lm) * C2_ + 8 * lh;
        const size_t prow = (((size_t)n * 64 + yy) * 64) * (size_t)C2_;
        const int x0 = lm + dx;
        const int x1 = 32 + lm + dx;
#pragma unroll
        for (int s = 0; s < 16; ++s) {
            long a = *(const long*)(wrow + 16 * s);
            long b0 = 0, b1 = 0;
            if (x0 >= 0) b0 = *(const long*)(S + prow + (size_t)(x0 * 256 + 16 * s + 8 * lh));
            if (x1 <= 63) b1 = *(const long*)(S + prow + (size_t)(x1 * 256 + 16 * s + 8 * lh));
            acc0 = __builtin_amdgcn_mfma_i32_32x32x16_i8(a, b0, acc0, 0, 0, 0);
            acc1 = __builtin_amdgcn_mfma_i32_32x32x16_i8(a, b1, acc1, 0, 0, 0);
        }
    }
#pragma unroll
    for (int r = 0; r < 16; ++r) {
        const int row = (r & 3) + 8 * (r >> 2) + 4 * lh;
        const int co = 32 * w + row;
        const float av = alpha[co], bv = bias[co];
        const size_t o = (((size_t)n * C_ + co) << 12) + (y << 6);
        out[o + lm]      = av * (float)acc0[r] + bv;
        out[o + 32 + lm] = av * (float)acc1[r] + bv;
    }
}

// ---- BatchNorm stats (atomic partials; zeroed in k_bw) ----
__global__ __launch_bounds__(256) void k_bnstats(const float* __restrict__ y,
                                                 float* __restrict__ bnS,
                                                 float* __restrict__ bnQ) {
    __shared__ float ssum[256], ssq[256];
    const int tid = threadIdx.x, o = blockIdx.x, n = blockIdx.y;
    const float* p = y + (((size_t)(n * C_ + o)) << 12);
    float s = 0.f, q = 0.f;
    for (int i = tid; i < HW_; i += 256) {
        float v = p[i];
        s += v; q += v * v;
    }
    ssum[tid] = s; ssq[tid] = q;
    __syncthreads();
    for (int st2 = 128; st2 > 0; st2 >>= 1) {
        if (tid < st2) { ssum[tid] += ssum[tid + st2]; ssq[tid] += ssq[tid + st2]; }
        __syncthreads();
    }
    if (tid == 0) {
        atomicAdd(&bnS[o], ssum[0]);
        atomicAdd(&bnQ[o], ssq[0]);
    }
}

// ---- final epilogue ----
__global__ __launch_bounds__(256) void k_final(const float* __restrict__ y3,
                                               const float* __restrict__ x,
                                               const float* __restrict__ c2,
                                               const float* __restrict__ bnS,
                                               const float* __restrict__ bnQ,
                                               const float* __restrict__ bng,
                                               const float* __restrict__ bnb,
                                               const float* __restrict__ b2v,
                                               const float* __restrict__ pa,
                                               const float* __restrict__ b3v,
                                               float* __restrict__ out) {
    const int idx = blockIdx.x * 256 + threadIdx.x;
    const int hw = idx & 4095;
    const int cb = idx >> 12;
    const int co = cb & 127;
    const int n = cb >> 7;
    const float mu = bnS[co] * (1.f / 32768.f);
    const float var = bnQ[co] * (1.f / 32768.f) - mu * mu;
    const float rstd = rsqrtf(var + EPS_);
    float v = (y3[idx] - mu) * rstd * bng[co] + bnb[co];
    const int ch0 = 2 * co;
    float p;
    if (co < 64) {
        p = 0.5f * (x[(((size_t)(n * C_ + ch0)) << 12) + hw] +
                    x[(((size_t)(n * C_ + ch0 + 1)) << 12) + hw]);
    } else {
        int d = ch0 - 128;
        p = 0.5f * (c2[(((size_t)(n * C_ + d)) << 12) + hw] +
                    c2[(((size_t)(n * C_ + d + 1)) << 12) + hw]);
    }
    v += p + b2v[n * 128 + co];
    v = (v >= 0.f) ? v : pa[co] * v;
    v += b3v[n * 128 + co];
    out[idx] = v;
}

// ---------------- launch ----------------
extern "C" void kernel_launch(void* const* d_in, const int* in_sizes, int n_in,
                              void* d_out, int out_size, void* d_ws, size_t ws_size,
                              hipStream_t stream) {
    const float* c       = (const float*)d_in[0];
    const float* x       = (const float*)d_in[1];
    const float* emb     = (const float*)d_in[2];
    const float* gn1_g   = (const float*)d_in[3];
    const float* gn1_b   = (const float*)d_in[4];
    const float* conv1_w = (const float*)d_in[5];
    const float* conv1_b = (const float*)d_in[6];
    const float* emb_w   = (const float*)d_in[7];
    const float* emb_b   = (const float*)d_in[8];
    const float* gn2_g   = (const float*)d_in[9];
    const float* gn2_b   = (const float*)d_in[10];
    const float* conv2_w = (const float*)d_in[11];
    const float* conv2_b = (const float*)d_in[12];
    const float* m1_w    = (const float*)d_in[13];
    const float* m1_b    = (const float*)d_in[14];
    const float* bconv_w = (const float*)d_in[15];
    const float* bconv_b = (const float*)d_in[16];
    const float* bn_g    = (const float*)d_in[17];
    const float* bn_b    = (const float*)d_in[18];
    const float* m2_w    = (const float*)d_in[19];
    const float* m2_b    = (const float*)d_in[20];
    const float* prelu_a = (const float*)d_in[21];
    const float* m3_w    = (const float*)d_in[22];
    const float* m3_b    = (const float*)d_in[23];
    float* out = (float*)d_out;

    // ws (~41.2 MB): a_buf 16MB | y_buf 16MB | actA(bf16)/S(i8) aliased 8MB |
    //                sgn 288KB | Wc1 288KB | Wc2 288KB | small vecs
    float* ws = (float*)d_ws;
    const size_t NCHW = (size_t)B_ * C_ * HW_;       // 4,194,304
    float*  a_buf = ws;
    float*  y_buf = ws + NCHW;
    unsigned short* actA = (unsigned short*)(ws + 2 * NCHW);   // 8 MB (NHWC bf16)
    int8_t* S     = (int8_t*)(ws + 2 * NCHW);                  // aliases actA (dead after conv2)
    int8_t* sgn   = (int8_t*)(ws + 2 * NCHW + NCHW / 2);       // 294912 B
    unsigned short* Wc1 = (unsigned short*)(ws + 2 * NCHW + NCHW / 2 + 73728);
    unsigned short* Wc2 = Wc1 + C_ * C_ * 9;                   // each 294912 B
    float*  alpha = ws + 2 * NCHW + NCHW / 2 + 73728 + 2 * 73728;
    float*  eo    = alpha + 128;
    float*  b1v   = eo + B_ * 256;
    float*  b2v   = b1v + B_ * 256;
    float*  b3v   = b2v + B_ * 128;
    float*  bnS   = b3v + B_ * 128;
    float*  bnQ   = bnS + 128;

    k_bw<<<C_, 256, 0, stream>>>(bconv_w, sgn, alpha, bnS, bnQ);
    k_wprep<<<(C_ * C_ * 9 + 255) / 256, 256, 0, stream>>>(conv1_w, conv2_w, Wc1, Wc2);
    k_emb<<<B_, 256, 0, stream>>>(emb, emb_w, emb_b, m1_w, m1_b, m2_w, m2_b,
                                  m3_w, m3_b, eo, b1v, b2v, b3v);
    k_gn1t<<<B_ * 32, 256, 0, stream>>>(c, gn1_g, gn1_b, actA);
    k_convm<false><<<dim3(64, B_), 256, 0, stream>>>(actA, Wc1, conv1_b, nullptr, y_buf);
    k_gn2t<<<B_ * 32, 256, 0, stream>>>(y_buf, gn2_g, gn2_b, eo, actA);
    k_convm<true><<<dim3(64, B_), 256, 0, stream>>>(actA, Wc2, conv2_b, c, a_buf); // a_buf = c2
    k_sign_t<<<dim3(64, B_), 256, 0, stream>>>(x, a_buf, b1v, S);                  // S overwrites actA
    k_bconv<<<dim3(64, B_), 256, 0, stream>>>(S, sgn, alpha, bconv_b, y_buf);      // y_buf = y3
    k_bnstats<<<dim3(C_, B_), 256, 0, stream>>>(y_buf, bnS, bnQ);
    k_final<<<NCHW / 256, 256, 0, stream>>>(y_buf, x, a_buf, bnS, bnQ, bn_g, bn_b,
                                            b2v, prelu_a, b3v, out);
}

// Round 6
// 314.651 us; speedup vs baseline: 3.7596x; 1.5061x over previous
//
#include <hip/hip_runtime.h>
#include <stdint.h>

// ConcatLayer_55654186221983 on MI355X (gfx950). All fp32 I/O.
// B=8, C=128, C2=256, H=W=64, EMB=512, GROUPS=32, EPS=1e-5.
// R6: conv kernels get LDS row-staging (zero-padded, branchless) + coalesced
// weight layout [kk][ci/8][co][8]. GN kernels widened to 1024 threads.

#define B_   8
#define C_   128
#define C2_  256
#define HW_  4096
#define EMB_ 512
#define EPS_ 1e-5f

typedef int   v16i __attribute__((ext_vector_type(16)));
typedef float v16f __attribute__((ext_vector_type(16)));
typedef short v8s  __attribute__((ext_vector_type(8)));

// LDS tile: 3 rows x 66 cols x (256 data + 16 pad) bytes
#define COLB 272
#define LDSZ (3 * 66 * COLB)

__device__ __forceinline__ float silu(float v) { return v / (1.f + expf(-v)); }
__device__ __forceinline__ unsigned short f2bf(float f) {
    unsigned int x = __float_as_uint(f);
    return (unsigned short)((x + 0x7FFFu + ((x >> 16) & 1u)) >> 16);  // RNE
}

// ---- binary weight prep: sgn[kk][ci/8][co][8] i8 + alpha[128]; zero BN sums ----
__global__ __launch_bounds__(256) void k_bw(const float* __restrict__ w,
                                            int8_t* __restrict__ sgn,
                                            float* __restrict__ alpha,
                                            float* __restrict__ bnS,
                                            float* __restrict__ bnQ) {
    __shared__ float red[256];
    const int tid = threadIdx.x, o = blockIdx.x;
    if (o == 0) { bnS[tid & 127] = 0.f; bnQ[tid & 127] = 0.f; }
    const float* wr = w + (size_t)o * (C2_ * 9);
    float s = 0.f;
    for (int i = tid; i < C2_ * 9; i += 256) s += fabsf(wr[i]);
    red[tid] = s;
    __syncthreads();
    for (int st = 128; st > 0; st >>= 1) {
        if (tid < st) red[tid] += red[tid + st];
        __syncthreads();
    }
    if (tid == 0) alpha[o] = red[0] / (float)(C2_ * 9);
    for (int kk = 0; kk < 9; ++kk) {
        float v = wr[tid * 9 + kk];   // tid == ci
        sgn[((size_t)(kk * 32 + (tid >> 3)) * C_ + o) * 8 + (tid & 7)] =
            (v > 0.f) ? (int8_t)1 : ((v < 0.f) ? (int8_t)(-1) : (int8_t)0);
    }
}

// ---- conv weight prep: [co][ci][3][3] fp32 -> [kk][ci/8][co][8] bf16 ----
__global__ __launch_bounds__(256) void k_wprep(const float* __restrict__ w1,
                                               const float* __restrict__ w2,
                                               unsigned short* __restrict__ Wc1,
                                               unsigned short* __restrict__ Wc2) {
    int i = blockIdx.x * 256 + threadIdx.x;
    if (i >= C_ * C_ * 9) return;
    int co = i / (C_ * 9);
    int rem = i - co * (C_ * 9);
    int ci = rem / 9, kk = rem - ci * 9;
    size_t d = ((size_t)(kk * 16 + (ci >> 3)) * C_ + co) * 8 + (ci & 7);
    Wc1[d] = f2bf(w1[i]);
    Wc2[d] = f2bf(w2[i]);
}

// ---------------- embedding MLPs ----------------
__global__ __launch_bounds__(256) void k_emb(
    const float* __restrict__ emb,
    const float* __restrict__ ew, const float* __restrict__ ebb,
    const float* __restrict__ m1w, const float* __restrict__ m1b,
    const float* __restrict__ m2w, const float* __restrict__ m2b,
    const float* __restrict__ m3w, const float* __restrict__ m3b,
    float* __restrict__ eo, float* __restrict__ b1,
    float* __restrict__ b2, float* __restrict__ b3) {
    __shared__ float se[EMB_];
    const int tid = threadIdx.x, bb = blockIdx.x;
    for (int i = tid; i < EMB_; i += 256) se[i] = silu(emb[bb * EMB_ + i]);
    __syncthreads();
    for (int o = tid; o < 768; o += 256) {
        const float* w;
        float bias;
        float* dst;
        if (o < 256)      { w = ew  + (size_t)o * EMB_;              bias = ebb[o];    dst = eo + bb * 256 + o; }
        else if (o < 512) { int r = o - 256; w = m1w + (size_t)r * EMB_; bias = m1b[r]; dst = b1 + bb * 256 + r; }
        else if (o < 640) { int r = o - 512; w = m2w + (size_t)r * EMB_; bias = m2b[r]; dst = b2 + bb * 128 + r; }
        else              { int r = o - 640; w = m3w + (size_t)r * EMB_; bias = m3b[r]; dst = b3 + bb * 128 + r; }
        float s = bias;
        for (int k = 0; k < EMB_; ++k) s += se[k] * w[k];
        *dst = s;
    }
}

// ---- GN1 + SiLU: NCHW fp32 in -> NHWC bf16 out (1024 threads) ----
__global__ __launch_bounds__(1024) void k_gn1t(const float* __restrict__ in,
                                               const float* __restrict__ g,
                                               const float* __restrict__ b,
                                               unsigned short* __restrict__ act) {
    __shared__ float ssum[1024], ssq[1024];
    __shared__ float s_mu, s_rstd;
    const int tid = threadIdx.x;
    const int n = blockIdx.x >> 5, grp = blockIdx.x & 31;
    const size_t base = ((size_t)(n * C_ + grp * 4)) << 12;
    float sum = 0.f, sq = 0.f;
    for (int i = tid; i < 16384; i += 1024) {
        float v = in[base + i];
        sum += v; sq += v * v;
    }
    ssum[tid] = sum; ssq[tid] = sq;
    __syncthreads();
    for (int st = 512; st > 0; st >>= 1) {
        if (tid < st) { ssum[tid] += ssum[tid + st]; ssq[tid] += ssq[tid + st]; }
        __syncthreads();
    }
    if (tid == 0) {
        float mu = ssum[0] * (1.f / 16384.f);
        float var = ssq[0] * (1.f / 16384.f) - mu * mu;
        s_mu = mu; s_rstd = rsqrtf(var + EPS_);
    }
    __syncthreads();
    const float mu = s_mu, rstd = s_rstd;
    float gg[4], bb[4];
#pragma unroll
    for (int j = 0; j < 4; ++j) { gg[j] = g[grp * 4 + j]; bb[j] = b[grp * 4 + j]; }
    for (int hw = tid; hw < HW_; hw += 1024) {
        union { unsigned short u[4]; uint2 v; } pk;
#pragma unroll
        for (int j = 0; j < 4; ++j) {
            float v = in[base + ((size_t)j << 12) + hw];
            pk.u[j] = f2bf(silu((v - mu) * rstd * gg[j] + bb[j]));
        }
        *(uint2*)(act + ((size_t)(n * HW_ + hw)) * C_ + grp * 4) = pk.v;
    }
}

// ---- GN2 + FiLM + SiLU: NCHW fp32 in -> NHWC bf16 out (1024 threads) ----
__global__ __launch_bounds__(1024) void k_gn2t(const float* __restrict__ in,
                                               const float* __restrict__ g,
                                               const float* __restrict__ b,
                                               const float* __restrict__ eo,
                                               unsigned short* __restrict__ act) {
    __shared__ float ssum[1024], ssq[1024];
    __shared__ float s_mu, s_rstd;
    const int tid = threadIdx.x;
    const int n = blockIdx.x >> 5, grp = blockIdx.x & 31;
    const size_t base = ((size_t)(n * C_ + grp * 4)) << 12;
    float sum = 0.f, sq = 0.f;
    for (int i = tid; i < 16384; i += 1024) {
        float v = in[base + i];
        sum += v; sq += v * v;
    }
    ssum[tid] = sum; ssq[tid] = sq;
    __syncthreads();
    for (int st = 512; st > 0; st >>= 1) {
        if (tid < st) { ssum[tid] += ssum[tid + st]; ssq[tid] += ssq[tid + st]; }
        __syncthreads();
    }
    if (tid == 0) {
        float mu = ssum[0] * (1.f / 16384.f);
        float var = ssq[0] * (1.f / 16384.f) - mu * mu;
        s_mu = mu; s_rstd = rsqrtf(var + EPS_);
    }
    __syncthreads();
    const float mu = s_mu, rstd = s_rstd;
    float sc[4], sh[4], gg[4], bb[4];
#pragma unroll
    for (int j = 0; j < 4; ++j) {
        int ch = grp * 4 + j;
        gg[j] = g[ch]; bb[j] = b[ch];
        sc[j] = 1.f + eo[n * 256 + ch];
        sh[j] = eo[n * 256 + 128 + ch];
    }
    for (int hw = tid; hw < HW_; hw += 1024) {
        union { unsigned short u[4]; uint2 v; } pk;
#pragma unroll
        for (int j = 0; j < 4; ++j) {
            float v = in[base + ((size_t)j << 12) + hw];
            float y = ((v - mu) * rstd * gg[j] + bb[j]) * sc[j] + sh[j];
            pk.u[j] = f2bf(silu(y));
        }
        *(uint2*)(act + ((size_t)(n * HW_ + hw)) * C_ + grp * 4) = pk.v;
    }
}

// ---- shared LDS row-staging: 3 rows x 64 cols of 256B -> padded cols 1..64 ----
// rowsrc[r] == nullptr -> zero row. 256 threads.
__device__ __forceinline__ void stage_rows(char* lds, const char* rs0,
                                           const char* rs1, const char* rs2) {
    const int tid = threadIdx.x;
    const char* rs[3] = {rs0, rs1, rs2};
    // zero boundary columns x=0 and x=65 (96 threads x 16B)
    if (tid < 96) {
        int r = tid / 32, q = tid & 31;
        int c = (q >> 4) ? 65 : 0, o = q & 15;
        *(float4*)(lds + (r * 66 + c) * COLB + o * 16) = make_float4(0.f, 0.f, 0.f, 0.f);
    }
    // 3 rows x 64 cols x 16 units of 16B = 3072 units, 12 per thread
#pragma unroll
    for (int u = 0; u < 12; ++u) {
        int idx = u * 256 + tid;
        int r = idx >> 10, rem = idx & 1023;
        int x = rem >> 4, o = rem & 15;
        char* dst = lds + (r * 66 + x + 1) * COLB + o * 16;
        if (rs[r]) *(float4*)dst = *(const float4*)(rs[r] + x * 256 + o * 16);
        else       *(float4*)dst = make_float4(0.f, 0.f, 0.f, 0.f);
    }
}

// ---- bf16 MFMA implicit-GEMM 3x3 conv with LDS-staged rows ----
// block (y, n); wave w -> co [32w,32w+32); two 32-px x-tiles.
// act: [n][y][x][ci=128] bf16; Wc: [kk][ci/8][co][8] bf16.
template <bool ADD_RES>
__global__ __launch_bounds__(256) void k_convm(const unsigned short* __restrict__ act,
                                               const unsigned short* __restrict__ Wc,
                                               const float* __restrict__ bias,
                                               const float* __restrict__ res,
                                               float* __restrict__ out) {
    __shared__ __align__(16) char lds[LDSZ];
    const int y = blockIdx.x;
    const int n = blockIdx.y;
    const char* base = (const char*)(act + ((size_t)n * 64) * 64 * C_);
    stage_rows(lds,
               (y > 0)  ? base + (size_t)(y - 1) * 16384 : nullptr,
               base + (size_t)y * 16384,
               (y < 63) ? base + (size_t)(y + 1) * 16384 : nullptr);
    __syncthreads();

    const int w = threadIdx.x >> 6;
    const int l = threadIdx.x & 63;
    const int lm = l & 31;
    const int lh = l >> 5;

    v16f acc0, acc1;
#pragma unroll
    for (int i = 0; i < 16; ++i) { acc0[i] = 0.f; acc1[i] = 0.f; }

#pragma unroll
    for (int kk = 0; kk < 9; ++kk) {
        const int r = kk / 3, dx = kk % 3 - 1;
        const char* col0 = lds + (r * 66 + lm + 1 + dx) * COLB + 16 * lh;
        const char* col1 = col0 + 32 * COLB;
        const unsigned short* wbase = Wc + (size_t)(kk * 16 + lh) * C_ * 8 + (32 * w + lm) * 8;
#pragma unroll
        for (int cb = 0; cb < 8; ++cb) {
            v8s a = *(const v8s*)(wbase + (size_t)(2 * cb) * C_ * 8);
            v8s b0 = *(const v8s*)(col0 + 32 * cb);
            v8s b1 = *(const v8s*)(col1 + 32 * cb);
            acc0 = __builtin_amdgcn_mfma_f32_32x32x16_bf16(a, b0, acc0, 0, 0, 0);
            acc1 = __builtin_amdgcn_mfma_f32_32x32x16_bf16(a, b1, acc1, 0, 0, 0);
        }
    }
#pragma unroll
    for (int r = 0; r < 16; ++r) {
        const int row = (r & 3) + 8 * (r >> 2) + 4 * lh;
        const int co = 32 * w + row;
        const float bv = bias[co];
        const size_t o = (((size_t)n * C_ + co) << 12) + (y << 6);
        float v0 = acc0[r] + bv, v1 = acc1[r] + bv;
        if (ADD_RES) { v0 += res[o + lm]; v1 += res[o + 32 + lm]; }
        out[o + lm] = v0;
        out[o + 32 + lm] = v1;
    }
}

// ---- sign + transpose: S[n][hw][256] int8 ----
__global__ __launch_bounds__(256) void k_sign_t(const float* __restrict__ x,
                                                const float* __restrict__ c2,
                                                const float* __restrict__ b1,
                                                int8_t* __restrict__ S) {
    __shared__ int lds[64 * 65];
    const int t = threadIdx.x;
    const int hw0 = blockIdx.x * 64, n = blockIdx.y;
    const int hwo = t & 63, chq0 = t >> 6;
    for (int it = 0; it < 16; ++it) {
        int chq = it * 4 + chq0;
        int pk = 0;
#pragma unroll
        for (int j = 0; j < 4; ++j) {
            int ch = 4 * chq + j;
            float v = (ch < 128) ? x[((size_t)(n * C_ + ch) << 12) + hw0 + hwo]
                                 : c2[((size_t)(n * C_ + ch - 128) << 12) + hw0 + hwo];
            v += b1[n * 256 + ch];
            int sg = (v > 0.f) ? 1 : ((v < 0.f) ? -1 : 0);
            pk |= (sg & 0xFF) << (8 * j);
        }
        lds[hwo * 65 + chq] = pk;
    }
    __syncthreads();
    int* So = (int*)S;
    for (int p = 0; p < 16; ++p) {
        int idx = p * 256 + t;
        int pl = idx >> 6, cq = idx & 63;
        So[((size_t)(n * HW_ + hw0 + pl)) * 64 + cq] = lds[pl * 65 + cq];
    }
}

// ---- binary conv: i8 MFMA implicit GEMM with LDS-staged rows ----
// S: [n][hw][ci=256] i8; Wk: [kk][ci/8][co][8] i8.
__global__ __launch_bounds__(256) void k_bconv(const int8_t* __restrict__ S,
                                               const int8_t* __restrict__ Wk,
                                               const float* __restrict__ alpha,
                                               const float* __restrict__ bias,
                                               float* __restrict__ out) {
    __shared__ __align__(16) char lds[LDSZ];
    const int y = blockIdx.x;
    const int n = blockIdx.y;
    const char* base = (const char*)(S + ((size_t)n * 64) * 64 * C2_);
    stage_rows(lds,
               (y > 0)  ? base + (size_t)(y - 1) * 16384 : nullptr,
               base + (size_t)y * 16384,
               (y < 63) ? base + (size_t)(y + 1) * 16384 : nullptr);
    __syncthreads();

    const int w = threadIdx.x >> 6;
    const int l = threadIdx.x & 63;
    const int lm = l & 31;
    const int lh = l >> 5;

    v16i acc0, acc1;
#pragma unroll
    for (int i = 0; i < 16; ++i) { acc0[i] = 0; acc1[i] = 0; }

#pragma unroll
    for (int kk = 0; kk < 9; ++kk) {
        const int r = kk / 3, dx = kk % 3 - 1;
        const char* col0 = lds + (r * 66 + lm + 1 + dx) * COLB + 8 * lh;
        const char* col1 = col0 + 32 * COLB;
        const int8_t* wbase = Wk + (size_t)(kk * 32 + lh) * C_ * 8 + (32 * w + lm) * 8;
#pragma unroll
        for (int s = 0; s < 16; ++s) {
            long a = *(const long*)(wbase + (size_t)(2 * s) * C_ * 8);
            long b0 = *(const long*)(col0 + 16 * s);
            long b1 = *(const long*)(col1 + 16 * s);
            acc0 = __builtin_amdgcn_mfma_i32_32x32x16_i8(a, b0, acc0, 0, 0, 0);
            acc1 = __builtin_amdgcn_mfma_i32_32x32x16_i8(a, b1, acc1, 0, 0, 0);
        }
    }
#pragma unroll
    for (int r = 0; r < 16; ++r) {
        const int row = (r & 3) + 8 * (r >> 2) + 4 * lh;
        const int co = 32 * w + row;
        const float av = alpha[co], bv = bias[co];
        const size_t o = (((size_t)n * C_ + co) << 12) + (y << 6);
        out[o + lm]      = av * (float)acc0[r] + bv;
        out[o + 32 + lm] = av * (float)acc1[r] + bv;
    }
}

// ---- BatchNorm stats (atomic partials; zeroed in k_bw) ----
__global__ __launch_bounds__(256) void k_bnstats(const float* __restrict__ y,
                                                 float* __restrict__ bnS,
                                                 float* __restrict__ bnQ) {
    __shared__ float ssum[256], ssq[256];
    const int tid = threadIdx.x, o = blockIdx.x, n = blockIdx.y;
    const float* p = y + (((size_t)(n * C_ + o)) << 12);
    float s = 0.f, q = 0.f;
    for (int i = tid; i < HW_; i += 256) {
        float v = p[i];
        s += v; q += v * v;
    }
    ssum[tid] = s; ssq[tid] = q;
    __syncthreads();
    for (int st2 = 128; st2 > 0; st2 >>= 1) {
        if (tid < st2) { ssum[tid] += ssum[tid + st2]; ssq[tid] += ssq[tid + st2]; }
        __syncthreads();
    }
    if (tid == 0) {
        atomicAdd(&bnS[o], ssum[0]);
        atomicAdd(&bnQ[o], ssq[0]);
    }
}

// ---- final epilogue ----
__global__ __launch_bounds__(256) void k_final(const float* __restrict__ y3,
                                               const float* __restrict__ x,
                                               const float* __restrict__ c2,
                                               const float* __restrict__ bnS,
                                               const float* __restrict__ bnQ,
                                               const float* __restrict__ bng,
                                               const float* __restrict__ bnb,
                                               const float* __restrict__ b2v,
                                               const float* __restrict__ pa,
                                               const float* __restrict__ b3v,
                                               float* __restrict__ out) {
    const int idx = blockIdx.x * 256 + threadIdx.x;
    const int hw = idx & 4095;
    const int cb = idx >> 12;
    const int co = cb & 127;
    const int n = cb >> 7;
    const float mu = bnS[co] * (1.f / 32768.f);
    const float var = bnQ[co] * (1.f / 32768.f) - mu * mu;
    const float rstd = rsqrtf(var + EPS_);
    float v = (y3[idx] - mu) * rstd * bng[co] + bnb[co];
    const int ch0 = 2 * co;
    float p;
    if (co < 64) {
        p = 0.5f * (x[(((size_t)(n * C_ + ch0)) << 12) + hw] +
                    x[(((size_t)(n * C_ + ch0 + 1)) << 12) + hw]);
    } else {
        int d = ch0 - 128;
        p = 0.5f * (c2[(((size_t)(n * C_ + d)) << 12) + hw] +
                    c2[(((size_t)(n * C_ + d + 1)) << 12) + hw]);
    }
    v += p + b2v[n * 128 + co];
    v = (v >= 0.f) ? v : pa[co] * v;
    v += b3v[n * 128 + co];
    out[idx] = v;
}

// ---------------- launch ----------------
extern "C" void kernel_launch(void* const* d_in, const int* in_sizes, int n_in,
                              void* d_out, int out_size, void* d_ws, size_t ws_size,
                              hipStream_t stream) {
    const float* c       = (const float*)d_in[0];
    const float* x       = (const float*)d_in[1];
    const float* emb     = (const float*)d_in[2];
    const float* gn1_g   = (const float*)d_in[3];
    const float* gn1_b   = (const float*)d_in[4];
    const float* conv1_w = (const float*)d_in[5];
    const float* conv1_b = (const float*)d_in[6];
    const float* emb_w   = (const float*)d_in[7];
    const float* emb_b   = (const float*)d_in[8];
    const float* gn2_g   = (const float*)d_in[9];
    const float* gn2_b   = (const float*)d_in[10];
    const float* conv2_w = (const float*)d_in[11];
    const float* conv2_b = (const float*)d_in[12];
    const float* m1_w    = (const float*)d_in[13];
    const float* m1_b    = (const float*)d_in[14];
    const float* bconv_w = (const float*)d_in[15];
    const float* bconv_b = (const float*)d_in[16];
    const float* bn_g    = (const float*)d_in[17];
    const float* bn_b    = (const float*)d_in[18];
    const float* m2_w    = (const float*)d_in[19];
    const float* m2_b    = (const float*)d_in[20];
    const float* prelu_a = (const float*)d_in[21];
    const float* m3_w    = (const float*)d_in[22];
    const float* m3_b    = (const float*)d_in[23];
    float* out = (float*)d_out;

    // ws (~41.2 MB): a_buf 16MB | y_buf 16MB | actA(bf16)/S(i8) aliased 8MB |
    //                sgn 288KB | Wc1 288KB | Wc2 288KB | small vecs
    float* ws = (float*)d_ws;
    const size_t NCHW = (size_t)B_ * C_ * HW_;       // 4,194,304
    float*  a_buf = ws;
    float*  y_buf = ws + NCHW;
    unsigned short* actA = (unsigned short*)(ws + 2 * NCHW);   // 8 MB (NHWC bf16)
    int8_t* S     = (int8_t*)(ws + 2 * NCHW);                  // aliases actA
    int8_t* sgn   = (int8_t*)(ws + 2 * NCHW + NCHW / 2);       // 294912 B
    unsigned short* Wc1 = (unsigned short*)(ws + 2 * NCHW + NCHW / 2 + 73728);
    unsigned short* Wc2 = Wc1 + C_ * C_ * 9;                   // each 294912 B
    float*  alpha = ws + 2 * NCHW + NCHW / 2 + 73728 + 2 * 73728;
    float*  eo    = alpha + 128;
    float*  b1v   = eo + B_ * 256;
    float*  b2v   = b1v + B_ * 256;
    float*  b3v   = b2v + B_ * 128;
    float*  bnS   = b3v + B_ * 128;
    float*  bnQ   = bnS + 128;

    k_bw<<<C_, 256, 0, stream>>>(bconv_w, sgn, alpha, bnS, bnQ);
    k_wprep<<<(C_ * C_ * 9 + 255) / 256, 256, 0, stream>>>(conv1_w, conv2_w, Wc1, Wc2);
    k_emb<<<B_, 256, 0, stream>>>(emb, emb_w, emb_b, m1_w, m1_b, m2_w, m2_b,
                                  m3_w, m3_b, eo, b1v, b2v, b3v);
    k_gn1t<<<B_ * 32, 1024, 0, stream>>>(c, gn1_g, gn1_b, actA);
    k_convm<false><<<dim3(64, B_), 256, 0, stream>>>(actA, Wc1, conv1_b, nullptr, y_buf);
    k_gn2t<<<B_ * 32, 1024, 0, stream>>>(y_buf, gn2_g, gn2_b, eo, actA);
    k_convm<true><<<dim3(64, B_), 256, 0, stream>>>(actA, Wc2, conv2_b, c, a_buf); // a_buf = c2
    k_sign_t<<<dim3(64, B_), 256, 0, stream>>>(x, a_buf, b1v, S);                  // S overwrites actA
    k_bconv<<<dim3(64, B_), 256, 0, stream>>>(S, sgn, alpha, bconv_b, y_buf);      // y_buf = y3
    k_bnstats<<<dim3(C_, B_), 256, 0, stream>>>(y_buf, bnS, bnQ);
    k_final<<<NCHW / 256, 256, 0, stream>>>(y_buf, x, a_buf, bnS, bnQ, bn_g, bn_b,
                                            b2v, prelu_a, b3v, out);
}

// Round 7
// 273.311 us; speedup vs baseline: 4.3282x; 1.1513x over previous
//
#include <hip/hip_runtime.h>
#include <stdint.h>

// ConcatLayer_55654186221983 on MI355X (gfx950). All fp32 I/O.
// B=8, C=128, C2=256, H=W=64, EMB=512, GROUPS=32, EPS=1e-5.
// R7: k_emb -> wave-per-output (768 waves, was 8 blocks / 0.3% occupancy);
//     float4 vectorization in k_final / k_bnstats.

#define B_   8
#define C_   128
#define C2_  256
#define HW_  4096
#define EMB_ 512
#define EPS_ 1e-5f

typedef int   v16i __attribute__((ext_vector_type(16)));
typedef float v16f __attribute__((ext_vector_type(16)));
typedef short v8s  __attribute__((ext_vector_type(8)));

// LDS tile: 3 rows x 66 cols x (256 data + 16 pad) bytes
#define COLB 272
#define LDSZ (3 * 66 * COLB)

__device__ __forceinline__ float silu(float v) { return v / (1.f + expf(-v)); }
__device__ __forceinline__ unsigned short f2bf(float f) {
    unsigned int x = __float_as_uint(f);
    return (unsigned short)((x + 0x7FFFu + ((x >> 16) & 1u)) >> 16);  // RNE
}

// ---- binary weight prep: sgn[kk][ci/8][co][8] i8 + alpha[128]; zero BN sums ----
__global__ __launch_bounds__(256) void k_bw(const float* __restrict__ w,
                                            int8_t* __restrict__ sgn,
                                            float* __restrict__ alpha,
                                            float* __restrict__ bnS,
                                            float* __restrict__ bnQ) {
    __shared__ float red[256];
    const int tid = threadIdx.x, o = blockIdx.x;
    if (o == 0) { bnS[tid & 127] = 0.f; bnQ[tid & 127] = 0.f; }
    const float* wr = w + (size_t)o * (C2_ * 9);
    float s = 0.f;
    for (int i = tid; i < C2_ * 9; i += 256) s += fabsf(wr[i]);
    red[tid] = s;
    __syncthreads();
    for (int st = 128; st > 0; st >>= 1) {
        if (tid < st) red[tid] += red[tid + st];
        __syncthreads();
    }
    if (tid == 0) alpha[o] = red[0] / (float)(C2_ * 9);
    for (int kk = 0; kk < 9; ++kk) {
        float v = wr[tid * 9 + kk];   // tid == ci
        sgn[((size_t)(kk * 32 + (tid >> 3)) * C_ + o) * 8 + (tid & 7)] =
            (v > 0.f) ? (int8_t)1 : ((v < 0.f) ? (int8_t)(-1) : (int8_t)0);
    }
}

// ---- conv weight prep: [co][ci][3][3] fp32 -> [kk][ci/8][co][8] bf16 ----
__global__ __launch_bounds__(256) void k_wprep(const float* __restrict__ w1,
                                               const float* __restrict__ w2,
                                               unsigned short* __restrict__ Wc1,
                                               unsigned short* __restrict__ Wc2) {
    int i = blockIdx.x * 256 + threadIdx.x;
    if (i >= C_ * C_ * 9) return;
    int co = i / (C_ * 9);
    int rem = i - co * (C_ * 9);
    int ci = rem / 9, kk = rem - ci * 9;
    size_t d = ((size_t)(kk * 16 + (ci >> 3)) * C_ + co) * 8 + (ci & 7);
    Wc1[d] = f2bf(w1[i]);
    Wc2[d] = f2bf(w2[i]);
}

// ---- silu(emb) precompute: sev[8][512] ----
__global__ __launch_bounds__(256) void k_se(const float* __restrict__ emb,
                                            float* __restrict__ sev) {
    int i = blockIdx.x * 256 + threadIdx.x;
    if (i < B_ * EMB_) sev[i] = silu(emb[i]);
}

// ---- embedding MLPs: one wave per output row (768 waves) ----
__global__ __launch_bounds__(256) void k_emb2(
    const float* __restrict__ sev,
    const float* __restrict__ ew, const float* __restrict__ ebb,
    const float* __restrict__ m1w, const float* __restrict__ m1b,
    const float* __restrict__ m2w, const float* __restrict__ m2b,
    const float* __restrict__ m3w, const float* __restrict__ m3b,
    float* __restrict__ eo, float* __restrict__ b1,
    float* __restrict__ b2, float* __restrict__ b3) {
    const int o = blockIdx.x * 4 + (threadIdx.x >> 6);   // wave-uniform
    const int l = threadIdx.x & 63;
    const float* w;
    float bias;
    float* dst;
    int dstride;
    if (o < 256)      { w = ew  + (size_t)o * EMB_;              bias = ebb[o];    dst = eo + o;  dstride = 256; }
    else if (o < 512) { int r = o - 256; w = m1w + (size_t)r * EMB_; bias = m1b[r]; dst = b1 + r; dstride = 256; }
    else if (o < 640) { int r = o - 512; w = m2w + (size_t)r * EMB_; bias = m2b[r]; dst = b2 + r; dstride = 128; }
    else              { int r = o - 640; w = m3w + (size_t)r * EMB_; bias = m3b[r]; dst = b3 + r; dstride = 128; }
    const float4 wa = *(const float4*)(w + 8 * l);
    const float4 wb = *(const float4*)(w + 8 * l + 4);
#pragma unroll
    for (int b = 0; b < B_; ++b) {
        const float* s = sev + b * EMB_ + 8 * l;
        float4 sa = *(const float4*)(s);
        float4 sb = *(const float4*)(s + 4);
        float p = wa.x * sa.x + wa.y * sa.y + wa.z * sa.z + wa.w * sa.w +
                  wb.x * sb.x + wb.y * sb.y + wb.z * sb.z + wb.w * sb.w;
#pragma unroll
        for (int off = 32; off > 0; off >>= 1) p += __shfl_down(p, off, 64);
        if (l == 0) dst[b * dstride] = bias + p;
    }
}

// ---- GN1 + SiLU: NCHW fp32 in -> NHWC bf16 out (1024 threads) ----
__global__ __launch_bounds__(1024) void k_gn1t(const float* __restrict__ in,
                                               const float* __restrict__ g,
                                               const float* __restrict__ b,
                                               unsigned short* __restrict__ act) {
    __shared__ float ssum[1024], ssq[1024];
    __shared__ float s_mu, s_rstd;
    const int tid = threadIdx.x;
    const int n = blockIdx.x >> 5, grp = blockIdx.x & 31;
    const size_t base = ((size_t)(n * C_ + grp * 4)) << 12;
    float sum = 0.f, sq = 0.f;
    for (int i = tid; i < 16384; i += 1024) {
        float v = in[base + i];
        sum += v; sq += v * v;
    }
    ssum[tid] = sum; ssq[tid] = sq;
    __syncthreads();
    for (int st = 512; st > 0; st >>= 1) {
        if (tid < st) { ssum[tid] += ssum[tid + st]; ssq[tid] += ssq[tid + st]; }
        __syncthreads();
    }
    if (tid == 0) {
        float mu = ssum[0] * (1.f / 16384.f);
        float var = ssq[0] * (1.f / 16384.f) - mu * mu;
        s_mu = mu; s_rstd = rsqrtf(var + EPS_);
    }
    __syncthreads();
    const float mu = s_mu, rstd = s_rstd;
    float gg[4], bb[4];
#pragma unroll
    for (int j = 0; j < 4; ++j) { gg[j] = g[grp * 4 + j]; bb[j] = b[grp * 4 + j]; }
    for (int hw = tid; hw < HW_; hw += 1024) {
        union { unsigned short u[4]; uint2 v; } pk;
#pragma unroll
        for (int j = 0; j < 4; ++j) {
            float v = in[base + ((size_t)j << 12) + hw];
            pk.u[j] = f2bf(silu((v - mu) * rstd * gg[j] + bb[j]));
        }
        *(uint2*)(act + ((size_t)(n * HW_ + hw)) * C_ + grp * 4) = pk.v;
    }
}

// ---- GN2 + FiLM + SiLU: NCHW fp32 in -> NHWC bf16 out (1024 threads) ----
__global__ __launch_bounds__(1024) void k_gn2t(const float* __restrict__ in,
                                               const float* __restrict__ g,
                                               const float* __restrict__ b,
                                               const float* __restrict__ eo,
                                               unsigned short* __restrict__ act) {
    __shared__ float ssum[1024], ssq[1024];
    __shared__ float s_mu, s_rstd;
    const int tid = threadIdx.x;
    const int n = blockIdx.x >> 5, grp = blockIdx.x & 31;
    const size_t base = ((size_t)(n * C_ + grp * 4)) << 12;
    float sum = 0.f, sq = 0.f;
    for (int i = tid; i < 16384; i += 1024) {
        float v = in[base + i];
        sum += v; sq += v * v;
    }
    ssum[tid] = sum; ssq[tid] = sq;
    __syncthreads();
    for (int st = 512; st > 0; st >>= 1) {
        if (tid < st) { ssum[tid] += ssum[tid + st]; ssq[tid] += ssq[tid + st]; }
        __syncthreads();
    }
    if (tid == 0) {
        float mu = ssum[0] * (1.f / 16384.f);
        float var = ssq[0] * (1.f / 16384.f) - mu * mu;
        s_mu = mu; s_rstd = rsqrtf(var + EPS_);
    }
    __syncthreads();
    const float mu = s_mu, rstd = s_rstd;
    float sc[4], sh[4], gg[4], bb[4];
#pragma unroll
    for (int j = 0; j < 4; ++j) {
        int ch = grp * 4 + j;
        gg[j] = g[ch]; bb[j] = b[ch];
        sc[j] = 1.f + eo[n * 256 + ch];
        sh[j] = eo[n * 256 + 128 + ch];
    }
    for (int hw = tid; hw < HW_; hw += 1024) {
        union { unsigned short u[4]; uint2 v; } pk;
#pragma unroll
        for (int j = 0; j < 4; ++j) {
            float v = in[base + ((size_t)j << 12) + hw];
            float y = ((v - mu) * rstd * gg[j] + bb[j]) * sc[j] + sh[j];
            pk.u[j] = f2bf(silu(y));
        }
        *(uint2*)(act + ((size_t)(n * HW_ + hw)) * C_ + grp * 4) = pk.v;
    }
}

// ---- shared LDS row-staging: 3 rows x 64 cols of 256B -> padded cols 1..64 ----
__device__ __forceinline__ void stage_rows(char* lds, const char* rs0,
                                           const char* rs1, const char* rs2) {
    const int tid = threadIdx.x;
    const char* rs[3] = {rs0, rs1, rs2};
    if (tid < 96) {
        int r = tid / 32, q = tid & 31;
        int c = (q >> 4) ? 65 : 0, o = q & 15;
        *(float4*)(lds + (r * 66 + c) * COLB + o * 16) = make_float4(0.f, 0.f, 0.f, 0.f);
    }
#pragma unroll
    for (int u = 0; u < 12; ++u) {
        int idx = u * 256 + tid;
        int r = idx >> 10, rem = idx & 1023;
        int x = rem >> 4, o = rem & 15;
        char* dst = lds + (r * 66 + x + 1) * COLB + o * 16;
        if (rs[r]) *(float4*)dst = *(const float4*)(rs[r] + x * 256 + o * 16);
        else       *(float4*)dst = make_float4(0.f, 0.f, 0.f, 0.f);
    }
}

// ---- bf16 MFMA implicit-GEMM 3x3 conv with LDS-staged rows ----
template <bool ADD_RES>
__global__ __launch_bounds__(256) void k_convm(const unsigned short* __restrict__ act,
                                               const unsigned short* __restrict__ Wc,
                                               const float* __restrict__ bias,
                                               const float* __restrict__ res,
                                               float* __restrict__ out) {
    __shared__ __align__(16) char lds[LDSZ];
    const int y = blockIdx.x;
    const int n = blockIdx.y;
    const char* base = (const char*)(act + ((size_t)n * 64) * 64 * C_);
    stage_rows(lds,
               (y > 0)  ? base + (size_t)(y - 1) * 16384 : nullptr,
               base + (size_t)y * 16384,
               (y < 63) ? base + (size_t)(y + 1) * 16384 : nullptr);
    __syncthreads();

    const int w = threadIdx.x >> 6;
    const int l = threadIdx.x & 63;
    const int lm = l & 31;
    const int lh = l >> 5;

    v16f acc0, acc1;
#pragma unroll
    for (int i = 0; i < 16; ++i) { acc0[i] = 0.f; acc1[i] = 0.f; }

#pragma unroll
    for (int kk = 0; kk < 9; ++kk) {
        const int r = kk / 3, dx = kk % 3 - 1;
        const char* col0 = lds + (r * 66 + lm + 1 + dx) * COLB + 16 * lh;
        const char* col1 = col0 + 32 * COLB;
        const unsigned short* wbase = Wc + (size_t)(kk * 16 + lh) * C_ * 8 + (32 * w + lm) * 8;
#pragma unroll
        for (int cb = 0; cb < 8; ++cb) {
            v8s a = *(const v8s*)(wbase + (size_t)(2 * cb) * C_ * 8);
            v8s b0 = *(const v8s*)(col0 + 32 * cb);
            v8s b1 = *(const v8s*)(col1 + 32 * cb);
            acc0 = __builtin_amdgcn_mfma_f32_32x32x16_bf16(a, b0, acc0, 0, 0, 0);
            acc1 = __builtin_amdgcn_mfma_f32_32x32x16_bf16(a, b1, acc1, 0, 0, 0);
        }
    }
#pragma unroll
    for (int r = 0; r < 16; ++r) {
        const int row = (r & 3) + 8 * (r >> 2) + 4 * lh;
        const int co = 32 * w + row;
        const float bv = bias[co];
        const size_t o = (((size_t)n * C_ + co) << 12) + (y << 6);
        float v0 = acc0[r] + bv, v1 = acc1[r] + bv;
        if (ADD_RES) { v0 += res[o + lm]; v1 += res[o + 32 + lm]; }
        out[o + lm] = v0;
        out[o + 32 + lm] = v1;
    }
}

// ---- sign + transpose: S[n][hw][256] int8 ----
__global__ __launch_bounds__(256) void k_sign_t(const float* __restrict__ x,
                                                const float* __restrict__ c2,
                                                const float* __restrict__ b1,
                                                int8_t* __restrict__ S) {
    __shared__ int lds[64 * 65];
    const int t = threadIdx.x;
    const int hw0 = blockIdx.x * 64, n = blockIdx.y;
    const int hwo = t & 63, chq0 = t >> 6;
    for (int it = 0; it < 16; ++it) {
        int chq = it * 4 + chq0;
        int pk = 0;
#pragma unroll
        for (int j = 0; j < 4; ++j) {
            int ch = 4 * chq + j;
            float v = (ch < 128) ? x[((size_t)(n * C_ + ch) << 12) + hw0 + hwo]
                                 : c2[((size_t)(n * C_ + ch - 128) << 12) + hw0 + hwo];
            v += b1[n * 256 + ch];
            int sg = (v > 0.f) ? 1 : ((v < 0.f) ? -1 : 0);
            pk |= (sg & 0xFF) << (8 * j);
        }
        lds[hwo * 65 + chq] = pk;
    }
    __syncthreads();
    int* So = (int*)S;
    for (int p = 0; p < 16; ++p) {
        int idx = p * 256 + t;
        int pl = idx >> 6, cq = idx & 63;
        So[((size_t)(n * HW_ + hw0 + pl)) * 64 + cq] = lds[pl * 65 + cq];
    }
}

// ---- binary conv: i8 MFMA implicit GEMM with LDS-staged rows ----
__global__ __launch_bounds__(256) void k_bconv(const int8_t* __restrict__ S,
                                               const int8_t* __restrict__ Wk,
                                               const float* __restrict__ alpha,
                                               const float* __restrict__ bias,
                                               float* __restrict__ out) {
    __shared__ __align__(16) char lds[LDSZ];
    const int y = blockIdx.x;
    const int n = blockIdx.y;
    const char* base = (const char*)(S + ((size_t)n * 64) * 64 * C2_);
    stage_rows(lds,
               (y > 0)  ? base + (size_t)(y - 1) * 16384 : nullptr,
               base + (size_t)y * 16384,
               (y < 63) ? base + (size_t)(y + 1) * 16384 : nullptr);
    __syncthreads();

    const int w = threadIdx.x >> 6;
    const int l = threadIdx.x & 63;
    const int lm = l & 31;
    const int lh = l >> 5;

    v16i acc0, acc1;
#pragma unroll
    for (int i = 0; i < 16; ++i) { acc0[i] = 0; acc1[i] = 0; }

#pragma unroll
    for (int kk = 0; kk < 9; ++kk) {
        const int r = kk / 3, dx = kk % 3 - 1;
        const char* col0 = lds + (r * 66 + lm + 1 + dx) * COLB + 8 * lh;
        const char* col1 = col0 + 32 * COLB;
        const int8_t* wbase = Wk + (size_t)(kk * 32 + lh) * C_ * 8 + (32 * w + lm) * 8;
#pragma unroll
        for (int s = 0; s < 16; ++s) {
            long a = *(const long*)(wbase + (size_t)(2 * s) * C_ * 8);
            long b0 = *(const long*)(col0 + 16 * s);
            long b1 = *(const long*)(col1 + 16 * s);
            acc0 = __builtin_amdgcn_mfma_i32_32x32x16_i8(a, b0, acc0, 0, 0, 0);
            acc1 = __builtin_amdgcn_mfma_i32_32x32x16_i8(a, b1, acc1, 0, 0, 0);
        }
    }
#pragma unroll
    for (int r = 0; r < 16; ++r) {
        const int row = (r & 3) + 8 * (r >> 2) + 4 * lh;
        const int co = 32 * w + row;
        const float av = alpha[co], bv = bias[co];
        const size_t o = (((size_t)n * C_ + co) << 12) + (y << 6);
        out[o + lm]      = av * (float)acc0[r] + bv;
        out[o + 32 + lm] = av * (float)acc1[r] + bv;
    }
}

// ---- BatchNorm stats (atomic partials; zeroed in k_bw), float4 reads ----
__global__ __launch_bounds__(256) void k_bnstats(const float* __restrict__ y,
                                                 float* __restrict__ bnS,
                                                 float* __restrict__ bnQ) {
    __shared__ float ssum[256], ssq[256];
    const int tid = threadIdx.x, o = blockIdx.x, n = blockIdx.y;
    const float* p = y + (((size_t)(n * C_ + o)) << 12);
    float s = 0.f, q = 0.f;
    for (int i = tid; i < HW_ / 4; i += 256) {
        float4 v = *(const float4*)(p + 4 * i);
        s += v.x + v.y + v.z + v.w;
        q += v.x * v.x + v.y * v.y + v.z * v.z + v.w * v.w;
    }
    ssum[tid] = s; ssq[tid] = q;
    __syncthreads();
    for (int st2 = 128; st2 > 0; st2 >>= 1) {
        if (tid < st2) { ssum[tid] += ssum[tid + st2]; ssq[tid] += ssq[tid + st2]; }
        __syncthreads();
    }
    if (tid == 0) {
        atomicAdd(&bnS[o], ssum[0]);
        atomicAdd(&bnQ[o], ssq[0]);
    }
}

// ---- final epilogue, float4 ----
__global__ __launch_bounds__(256) void k_final(const float* __restrict__ y3,
                                               const float* __restrict__ x,
                                               const float* __restrict__ c2,
                                               const float* __restrict__ bnS,
                                               const float* __restrict__ bnQ,
                                               const float* __restrict__ bng,
                                               const float* __restrict__ bnb,
                                               const float* __restrict__ b2v,
                                               const float* __restrict__ pa,
                                               const float* __restrict__ b3v,
                                               float* __restrict__ out) {
    const int idx4 = blockIdx.x * 256 + threadIdx.x;   // < 1,048,576
    const int hw = (idx4 & 1023) * 4;
    const int cb = idx4 >> 10;
    const int co = cb & 127;
    const int n = cb >> 7;
    const float mu = bnS[co] * (1.f / 32768.f);
    const float var = bnQ[co] * (1.f / 32768.f) - mu * mu;
    const float rstd = rsqrtf(var + EPS_);
    const float gm = rstd * bng[co];
    const float bt = bnb[co] - mu * gm;
    const size_t obase = (((size_t)(n * C_ + co)) << 12) + hw;
    float4 v = *(const float4*)(y3 + obase);
    v.x = v.x * gm + bt; v.y = v.y * gm + bt; v.z = v.z * gm + bt; v.w = v.w * gm + bt;

    const int ch0 = 2 * co;
    float4 pA, pB;
    if (co < 64) {
        pA = *(const float4*)(x + (((size_t)(n * C_ + ch0)) << 12) + hw);
        pB = *(const float4*)(x + (((size_t)(n * C_ + ch0 + 1)) << 12) + hw);
    } else {
        int d = ch0 - 128;
        pA = *(const float4*)(c2 + (((size_t)(n * C_ + d)) << 12) + hw);
        pB = *(const float4*)(c2 + (((size_t)(n * C_ + d + 1)) << 12) + hw);
    }
    const float bias2 = b2v[n * 128 + co];
    const float aP = pa[co];
    const float bias3 = b3v[n * 128 + co];
    float4 r;
    float t;
    t = v.x + 0.5f * (pA.x + pB.x) + bias2; t = (t >= 0.f) ? t : aP * t; r.x = t + bias3;
    t = v.y + 0.5f * (pA.y + pB.y) + bias2; t = (t >= 0.f) ? t : aP * t; r.y = t + bias3;
    t = v.z + 0.5f * (pA.z + pB.z) + bias2; t = (t >= 0.f) ? t : aP * t; r.z = t + bias3;
    t = v.w + 0.5f * (pA.w + pB.w) + bias2; t = (t >= 0.f) ? t : aP * t; r.w = t + bias3;
    *(float4*)(out + obase) = r;
}

// ---------------- launch ----------------
extern "C" void kernel_launch(void* const* d_in, const int* in_sizes, int n_in,
                              void* d_out, int out_size, void* d_ws, size_t ws_size,
                              hipStream_t stream) {
    const float* c       = (const float*)d_in[0];
    const float* x       = (const float*)d_in[1];
    const float* emb     = (const float*)d_in[2];
    const float* gn1_g   = (const float*)d_in[3];
    const float* gn1_b   = (const float*)d_in[4];
    const float* conv1_w = (const float*)d_in[5];
    const float* conv1_b = (const float*)d_in[6];
    const float* emb_w   = (const float*)d_in[7];
    const float* emb_b   = (const float*)d_in[8];
    const float* gn2_g   = (const float*)d_in[9];
    const float* gn2_b   = (const float*)d_in[10];
    const float* conv2_w = (const float*)d_in[11];
    const float* conv2_b = (const float*)d_in[12];
    const float* m1_w    = (const float*)d_in[13];
    const float* m1_b    = (const float*)d_in[14];
    const float* bconv_w = (const float*)d_in[15];
    const float* bconv_b = (const float*)d_in[16];
    const float* bn_g    = (const float*)d_in[17];
    const float* bn_b    = (const float*)d_in[18];
    const float* m2_w    = (const float*)d_in[19];
    const float* m2_b    = (const float*)d_in[20];
    const float* prelu_a = (const float*)d_in[21];
    const float* m3_w    = (const float*)d_in[22];
    const float* m3_b    = (const float*)d_in[23];
    float* out = (float*)d_out;

    // ws (~41.2 MB): a_buf 16MB | y_buf 16MB | actA(bf16)/S(i8) aliased 8MB |
    //                sgn 288KB | Wc1 288KB | Wc2 288KB | small vecs
    float* ws = (float*)d_ws;
    const size_t NCHW = (size_t)B_ * C_ * HW_;       // 4,194,304
    float*  a_buf = ws;
    float*  y_buf = ws + NCHW;
    unsigned short* actA = (unsigned short*)(ws + 2 * NCHW);   // 8 MB (NHWC bf16)
    int8_t* S     = (int8_t*)(ws + 2 * NCHW);                  // aliases actA
    int8_t* sgn   = (int8_t*)(ws + 2 * NCHW + NCHW / 2);       // 294912 B
    unsigned short* Wc1 = (unsigned short*)(ws + 2 * NCHW + NCHW / 2 + 73728);
    unsigned short* Wc2 = Wc1 + C_ * C_ * 9;                   // each 294912 B
    float*  alpha = ws + 2 * NCHW + NCHW / 2 + 73728 + 2 * 73728;
    float*  eo    = alpha + 128;
    float*  b1v   = eo + B_ * 256;
    float*  b2v   = b1v + B_ * 256;
    float*  b3v   = b2v + B_ * 128;
    float*  bnS   = b3v + B_ * 128;
    float*  bnQ   = bnS + 128;
    float*  sev   = bnQ + 128;                                  // 4096 floats

    k_bw<<<C_, 256, 0, stream>>>(bconv_w, sgn, alpha, bnS, bnQ);
    k_wprep<<<(C_ * C_ * 9 + 255) / 256, 256, 0, stream>>>(conv1_w, conv2_w, Wc1, Wc2);
    k_se<<<(B_ * EMB_ + 255) / 256, 256, 0, stream>>>(emb, sev);
    k_emb2<<<192, 256, 0, stream>>>(sev, emb_w, emb_b, m1_w, m1_b, m2_w, m2_b,
                                    m3_w, m3_b, eo, b1v, b2v, b3v);
    k_gn1t<<<B_ * 32, 1024, 0, stream>>>(c, gn1_g, gn1_b, actA);
    k_convm<false><<<dim3(64, B_), 256, 0, stream>>>(actA, Wc1, conv1_b, nullptr, y_buf);
    k_gn2t<<<B_ * 32, 1024, 0, stream>>>(y_buf, gn2_g, gn2_b, eo, actA);
    k_convm<true><<<dim3(64, B_), 256, 0, stream>>>(actA, Wc2, conv2_b, c, a_buf); // a_buf = c2
    k_sign_t<<<dim3(64, B_), 256, 0, stream>>>(x, a_buf, b1v, S);                  // S overwrites actA
    k_bconv<<<dim3(64, B_), 256, 0, stream>>>(S, sgn, alpha, bconv_b, y_buf);      // y_buf = y3
    k_bnstats<<<dim3(C_, B_), 256, 0, stream>>>(y_buf, bnS, bnQ);
    k_final<<<NCHW / 1024, 256, 0, stream>>>(y_buf, x, a_buf, bnS, bnQ, bn_g, bn_b,
                                             b2v, prelu_a, b3v, out);
}

// Round 8
// 266.124 us; speedup vs baseline: 4.4451x; 1.0270x over previous
//
#include <hip/hip_runtime.h>
#include <stdint.h>

// ConcatLayer_55654186221983 on MI355X (gfx950). All fp32 I/O.
// B=8, C=128, C2=256, H=W=64, EMB=512, GROUPS=32, EPS=1e-5.
// R8: bconv -> mfma_i32_32x32x32_i8 (16B frags, half the MFMA+LDS instrs),
//     BN stats fused into bconv epilogue (shuffle reduce + atomics),
//     k_bw+k_wprep merged, silu inlined in k_emb2 (11 -> 9 dispatches),
//     float4 GN stats.

#define B_   8
#define C_   128
#define C2_  256
#define HW_  4096
#define EMB_ 512
#define EPS_ 1e-5f

typedef int   v16i __attribute__((ext_vector_type(16)));
typedef float v16f __attribute__((ext_vector_type(16)));
typedef short v8s  __attribute__((ext_vector_type(8)));
typedef int   v4i  __attribute__((ext_vector_type(4)));

// LDS tile: 3 rows x 66 cols x (256 data + 16 pad) bytes
#define COLB 272
#define LDSZ (3 * 66 * COLB)

__device__ __forceinline__ float silu(float v) { return v / (1.f + expf(-v)); }
__device__ __forceinline__ unsigned short f2bf(float f) {
    unsigned int x = __float_as_uint(f);
    return (unsigned short)((x + 0x7FFFu + ((x >> 16) & 1u)) >> 16);  // RNE
}

// ---- merged prep: blocks 0..127 = binary weights (+zero BN sums);
//      blocks 128..703 = conv weight relayout ----
// sgn layout: [kk][ci/16][co][16] i8 (16B frags for K=32 MFMA)
__global__ __launch_bounds__(256) void k_prep(const float* __restrict__ w,
                                              int8_t* __restrict__ sgn,
                                              float* __restrict__ alpha,
                                              float* __restrict__ bnS,
                                              float* __restrict__ bnQ,
                                              const float* __restrict__ w1,
                                              const float* __restrict__ w2,
                                              unsigned short* __restrict__ Wc1,
                                              unsigned short* __restrict__ Wc2) {
    const int blk = blockIdx.x, tid = threadIdx.x;
    if (blk < 128) {
        __shared__ float red[256];
        const int o = blk;
        if (o == 0 && tid < 128) { bnS[tid] = 0.f; bnQ[tid] = 0.f; }
        const float* wr = w + (size_t)o * (C2_ * 9);
        float s = 0.f;
        for (int i = tid; i < C2_ * 9; i += 256) s += fabsf(wr[i]);
        red[tid] = s;
        __syncthreads();
        for (int st = 128; st > 0; st >>= 1) {
            if (tid < st) red[tid] += red[tid + st];
            __syncthreads();
        }
        if (tid == 0) alpha[o] = red[0] / (float)(C2_ * 9);
        for (int kk = 0; kk < 9; ++kk) {
            float v = wr[tid * 9 + kk];   // tid == ci
            sgn[((size_t)(kk * 16 + (tid >> 4)) * C_ + o) * 16 + (tid & 15)] =
                (v > 0.f) ? (int8_t)1 : ((v < 0.f) ? (int8_t)(-1) : (int8_t)0);
        }
    } else {
        int i = (blk - 128) * 256 + tid;
        if (i >= C_ * C_ * 9) return;
        int co = i / (C_ * 9);
        int rem = i - co * (C_ * 9);
        int ci = rem / 9, kk = rem - ci * 9;
        size_t d = ((size_t)(kk * 16 + (ci >> 3)) * C_ + co) * 8 + (ci & 7);
        Wc1[d] = f2bf(w1[i]);
        Wc2[d] = f2bf(w2[i]);
    }
}

// ---- embedding MLPs: one wave per output row (768 waves), silu inline ----
__global__ __launch_bounds__(256) void k_emb2(
    const float* __restrict__ emb,
    const float* __restrict__ ew, const float* __restrict__ ebb,
    const float* __restrict__ m1w, const float* __restrict__ m1b,
    const float* __restrict__ m2w, const float* __restrict__ m2b,
    const float* __restrict__ m3w, const float* __restrict__ m3b,
    float* __restrict__ eo, float* __restrict__ b1,
    float* __restrict__ b2, float* __restrict__ b3) {
    const int o = blockIdx.x * 4 + (threadIdx.x >> 6);   // wave-uniform
    const int l = threadIdx.x & 63;
    const float* w;
    float bias;
    float* dst;
    int dstride;
    if (o < 256)      { w = ew  + (size_t)o * EMB_;              bias = ebb[o];    dst = eo + o;  dstride = 256; }
    else if (o < 512) { int r = o - 256; w = m1w + (size_t)r * EMB_; bias = m1b[r]; dst = b1 + r; dstride = 256; }
    else if (o < 640) { int r = o - 512; w = m2w + (size_t)r * EMB_; bias = m2b[r]; dst = b2 + r; dstride = 128; }
    else              { int r = o - 640; w = m3w + (size_t)r * EMB_; bias = m3b[r]; dst = b3 + r; dstride = 128; }
    const float4 wa = *(const float4*)(w + 8 * l);
    const float4 wb = *(const float4*)(w + 8 * l + 4);
#pragma unroll
    for (int b = 0; b < B_; ++b) {
        const float* s = emb + b * EMB_ + 8 * l;
        float4 sa = *(const float4*)(s);
        float4 sb = *(const float4*)(s + 4);
        float p = wa.x * silu(sa.x) + wa.y * silu(sa.y) + wa.z * silu(sa.z) + wa.w * silu(sa.w) +
                  wb.x * silu(sb.x) + wb.y * silu(sb.y) + wb.z * silu(sb.z) + wb.w * silu(sb.w);
#pragma unroll
        for (int off = 32; off > 0; off >>= 1) p += __shfl_down(p, off, 64);
        if (l == 0) dst[b * dstride] = bias + p;
    }
}

// ---- GN1 + SiLU: NCHW fp32 in -> NHWC bf16 out (1024 threads) ----
__global__ __launch_bounds__(1024) void k_gn1t(const float* __restrict__ in,
                                               const float* __restrict__ g,
                                               const float* __restrict__ b,
                                               unsigned short* __restrict__ act) {
    __shared__ float ssum[1024], ssq[1024];
    __shared__ float s_mu, s_rstd;
    const int tid = threadIdx.x;
    const int n = blockIdx.x >> 5, grp = blockIdx.x & 31;
    const size_t base = ((size_t)(n * C_ + grp * 4)) << 12;
    float sum = 0.f, sq = 0.f;
    const float4* in4 = (const float4*)(in + base);
    for (int i = tid; i < 4096; i += 1024) {
        float4 v = in4[i];
        sum += v.x + v.y + v.z + v.w;
        sq += v.x * v.x + v.y * v.y + v.z * v.z + v.w * v.w;
    }
    ssum[tid] = sum; ssq[tid] = sq;
    __syncthreads();
    for (int st = 512; st > 0; st >>= 1) {
        if (tid < st) { ssum[tid] += ssum[tid + st]; ssq[tid] += ssq[tid + st]; }
        __syncthreads();
    }
    if (tid == 0) {
        float mu = ssum[0] * (1.f / 16384.f);
        float var = ssq[0] * (1.f / 16384.f) - mu * mu;
        s_mu = mu; s_rstd = rsqrtf(var + EPS_);
    }
    __syncthreads();
    const float mu = s_mu, rstd = s_rstd;
    float gg[4], bb[4];
#pragma unroll
    for (int j = 0; j < 4; ++j) { gg[j] = g[grp * 4 + j]; bb[j] = b[grp * 4 + j]; }
    for (int hw = tid; hw < HW_; hw += 1024) {
        union { unsigned short u[4]; uint2 v; } pk;
#pragma unroll
        for (int j = 0; j < 4; ++j) {
            float v = in[base + ((size_t)j << 12) + hw];
            pk.u[j] = f2bf(silu((v - mu) * rstd * gg[j] + bb[j]));
        }
        *(uint2*)(act + ((size_t)(n * HW_ + hw)) * C_ + grp * 4) = pk.v;
    }
}

// ---- GN2 + FiLM + SiLU: NCHW fp32 in -> NHWC bf16 out (1024 threads) ----
__global__ __launch_bounds__(1024) void k_gn2t(const float* __restrict__ in,
                                               const float* __restrict__ g,
                                               const float* __restrict__ b,
                                               const float* __restrict__ eo,
                                               unsigned short* __restrict__ act) {
    __shared__ float ssum[1024], ssq[1024];
    __shared__ float s_mu, s_rstd;
    const int tid = threadIdx.x;
    const int n = blockIdx.x >> 5, grp = blockIdx.x & 31;
    const size_t base = ((size_t)(n * C_ + grp * 4)) << 12;
    float sum = 0.f, sq = 0.f;
    const float4* in4 = (const float4*)(in + base);
    for (int i = tid; i < 4096; i += 1024) {
        float4 v = in4[i];
        sum += v.x + v.y + v.z + v.w;
        sq += v.x * v.x + v.y * v.y + v.z * v.z + v.w * v.w;
    }
    ssum[tid] = sum; ssq[tid] = sq;
    __syncthreads();
    for (int st = 512; st > 0; st >>= 1) {
        if (tid < st) { ssum[tid] += ssum[tid + st]; ssq[tid] += ssq[tid + st]; }
        __syncthreads();
    }
    if (tid == 0) {
        float mu = ssum[0] * (1.f / 16384.f);
        float var = ssq[0] * (1.f / 16384.f) - mu * mu;
        s_mu = mu; s_rstd = rsqrtf(var + EPS_);
    }
    __syncthreads();
    const float mu = s_mu, rstd = s_rstd;
    float sc[4], sh[4], gg[4], bb[4];
#pragma unroll
    for (int j = 0; j < 4; ++j) {
        int ch = grp * 4 + j;
        gg[j] = g[ch]; bb[j] = b[ch];
        sc[j] = 1.f + eo[n * 256 + ch];
        sh[j] = eo[n * 256 + 128 + ch];
    }
    for (int hw = tid; hw < HW_; hw += 1024) {
        union { unsigned short u[4]; uint2 v; } pk;
#pragma unroll
        for (int j = 0; j < 4; ++j) {
            float v = in[base + ((size_t)j << 12) + hw];
            float y = ((v - mu) * rstd * gg[j] + bb[j]) * sc[j] + sh[j];
            pk.u[j] = f2bf(silu(y));
        }
        *(uint2*)(act + ((size_t)(n * HW_ + hw)) * C_ + grp * 4) = pk.v;
    }
}

// ---- shared LDS row-staging: 3 rows x 64 cols of 256B -> padded cols 1..64 ----
__device__ __forceinline__ void stage_rows(char* lds, const char* rs0,
                                           const char* rs1, const char* rs2) {
    const int tid = threadIdx.x;
    const char* rs[3] = {rs0, rs1, rs2};
    if (tid < 96) {
        int r = tid / 32, q = tid & 31;
        int c = (q >> 4) ? 65 : 0, o = q & 15;
        *(float4*)(lds + (r * 66 + c) * COLB + o * 16) = make_float4(0.f, 0.f, 0.f, 0.f);
    }
#pragma unroll
    for (int u = 0; u < 12; ++u) {
        int idx = u * 256 + tid;
        int r = idx >> 10, rem = idx & 1023;
        int x = rem >> 4, o = rem & 15;
        char* dst = lds + (r * 66 + x + 1) * COLB + o * 16;
        if (rs[r]) *(float4*)dst = *(const float4*)(rs[r] + x * 256 + o * 16);
        else       *(float4*)dst = make_float4(0.f, 0.f, 0.f, 0.f);
    }
}

// ---- bf16 MFMA implicit-GEMM 3x3 conv with LDS-staged rows ----
template <bool ADD_RES>
__global__ __launch_bounds__(256) void k_convm(const unsigned short* __restrict__ act,
                                               const unsigned short* __restrict__ Wc,
                                               const float* __restrict__ bias,
                                               const float* __restrict__ res,
                                               float* __restrict__ out) {
    __shared__ __align__(16) char lds[LDSZ];
    const int y = blockIdx.x;
    const int n = blockIdx.y;
    const char* base = (const char*)(act + ((size_t)n * 64) * 64 * C_);
    stage_rows(lds,
               (y > 0)  ? base + (size_t)(y - 1) * 16384 : nullptr,
               base + (size_t)y * 16384,
               (y < 63) ? base + (size_t)(y + 1) * 16384 : nullptr);
    __syncthreads();

    const int w = threadIdx.x >> 6;
    const int l = threadIdx.x & 63;
    const int lm = l & 31;
    const int lh = l >> 5;

    v16f acc0, acc1;
#pragma unroll
    for (int i = 0; i < 16; ++i) { acc0[i] = 0.f; acc1[i] = 0.f; }

#pragma unroll
    for (int kk = 0; kk < 9; ++kk) {
        const int r = kk / 3, dx = kk % 3 - 1;
        const char* col0 = lds + (r * 66 + lm + 1 + dx) * COLB + 16 * lh;
        const char* col1 = col0 + 32 * COLB;
        const unsigned short* wbase = Wc + (size_t)(kk * 16 + lh) * C_ * 8 + (32 * w + lm) * 8;
#pragma unroll
        for (int cb = 0; cb < 8; ++cb) {
            v8s a = *(const v8s*)(wbase + (size_t)(2 * cb) * C_ * 8);
            v8s b0 = *(const v8s*)(col0 + 32 * cb);
            v8s b1 = *(const v8s*)(col1 + 32 * cb);
            acc0 = __builtin_amdgcn_mfma_f32_32x32x16_bf16(a, b0, acc0, 0, 0, 0);
            acc1 = __builtin_amdgcn_mfma_f32_32x32x16_bf16(a, b1, acc1, 0, 0, 0);
        }
    }
#pragma unroll
    for (int r = 0; r < 16; ++r) {
        const int row = (r & 3) + 8 * (r >> 2) + 4 * lh;
        const int co = 32 * w + row;
        const float bv = bias[co];
        const size_t o = (((size_t)n * C_ + co) << 12) + (y << 6);
        float v0 = acc0[r] + bv, v1 = acc1[r] + bv;
        if (ADD_RES) { v0 += res[o + lm]; v1 += res[o + 32 + lm]; }
        out[o + lm] = v0;
        out[o + 32 + lm] = v1;
    }
}

// ---- sign + transpose: S[n][hw][256] int8 ----
__global__ __launch_bounds__(256) void k_sign_t(const float* __restrict__ x,
                                                const float* __restrict__ c2,
                                                const float* __restrict__ b1,
                                                int8_t* __restrict__ S) {
    __shared__ int lds[64 * 65];
    const int t = threadIdx.x;
    const int hw0 = blockIdx.x * 64, n = blockIdx.y;
    const int hwo = t & 63, chq0 = t >> 6;
    for (int it = 0; it < 16; ++it) {
        int chq = it * 4 + chq0;
        int pk = 0;
#pragma unroll
        for (int j = 0; j < 4; ++j) {
            int ch = 4 * chq + j;
            float v = (ch < 128) ? x[((size_t)(n * C_ + ch) << 12) + hw0 + hwo]
                                 : c2[((size_t)(n * C_ + ch - 128) << 12) + hw0 + hwo];
            v += b1[n * 256 + ch];
            int sg = (v > 0.f) ? 1 : ((v < 0.f) ? -1 : 0);
            pk |= (sg & 0xFF) << (8 * j);
        }
        lds[hwo * 65 + chq] = pk;
    }
    __syncthreads();
    int* So = (int*)S;
    for (int p = 0; p < 16; ++p) {
        int idx = p * 256 + t;
        int pl = idx >> 6, cq = idx & 63;
        So[((size_t)(n * HW_ + hw0 + pl)) * 64 + cq] = lds[pl * 65 + cq];
    }
}

// ---- binary conv: i8 K=32 MFMA implicit GEMM + fused BN stats ----
// S: [n][hw][ci=256] i8; Wk: [kk][ci/16][co][16] i8.
__global__ __launch_bounds__(256) void k_bconv(const int8_t* __restrict__ S,
                                               const int8_t* __restrict__ Wk,
                                               const float* __restrict__ alpha,
                                               const float* __restrict__ bias,
                                               float* __restrict__ out,
                                               float* __restrict__ bnS,
                                               float* __restrict__ bnQ) {
    __shared__ __align__(16) char lds[LDSZ];
    const int y = blockIdx.x;
    const int n = blockIdx.y;
    const char* base = (const char*)(S + ((size_t)n * 64) * 64 * C2_);
    stage_rows(lds,
               (y > 0)  ? base + (size_t)(y - 1) * 16384 : nullptr,
               base + (size_t)y * 16384,
               (y < 63) ? base + (size_t)(y + 1) * 16384 : nullptr);
    __syncthreads();

    const int w = threadIdx.x >> 6;
    const int l = threadIdx.x & 63;
    const int lm = l & 31;
    const int lh = l >> 5;

    v16i acc0, acc1;
#pragma unroll
    for (int i = 0; i < 16; ++i) { acc0[i] = 0; acc1[i] = 0; }

#pragma unroll
    for (int kk = 0; kk < 9; ++kk) {
        const int r = kk / 3, dx = kk % 3 - 1;
        const char* col0 = lds + (r * 66 + lm + 1 + dx) * COLB + 16 * lh;
        const char* col1 = col0 + 32 * COLB;
        const int8_t* wbase = Wk + (size_t)(kk * 16 + lh) * C_ * 16 + (32 * w + lm) * 16;
#pragma unroll
        for (int s = 0; s < 8; ++s) {
            v4i a = *(const v4i*)(wbase + (size_t)(2 * s) * C_ * 16);
            v4i b0 = *(const v4i*)(col0 + 32 * s);
            v4i b1 = *(const v4i*)(col1 + 32 * s);
            acc0 = __builtin_amdgcn_mfma_i32_32x32x32_i8(a, b0, acc0, 0, 0, 0);
            acc1 = __builtin_amdgcn_mfma_i32_32x32x32_i8(a, b1, acc1, 0, 0, 0);
        }
    }

    float pr[16], qr[16];
#pragma unroll
    for (int r = 0; r < 16; ++r) {
        const int row = (r & 3) + 8 * (r >> 2) + 4 * lh;
        const int co = 32 * w + row;
        const float av = alpha[co], bv = bias[co];
        const size_t o = (((size_t)n * C_ + co) << 12) + (y << 6);
        float v0 = av * (float)acc0[r] + bv;
        float v1 = av * (float)acc1[r] + bv;
        out[o + lm]      = v0;
        out[o + 32 + lm] = v1;
        pr[r] = v0 + v1;
        qr[r] = v0 * v0 + v1 * v1;
    }

    // fused BN partials: reduce over x (32 lanes per half), stash in LDS, atomic
    __syncthreads();                       // staging LDS reads all done
    float* ldsS = (float*)lds;
    float* ldsQ = (float*)lds + 128;
#pragma unroll
    for (int r = 0; r < 16; ++r) {
        float p = pr[r], q = qr[r];
#pragma unroll
        for (int m = 16; m > 0; m >>= 1) {
            p += __shfl_xor(p, m, 64);
            q += __shfl_xor(q, m, 64);
        }
        if (lm == 0) {
            const int row = (r & 3) + 8 * (r >> 2) + 4 * lh;
            const int co = 32 * w + row;
            ldsS[co] = p;
            ldsQ[co] = q;
        }
    }
    __syncthreads();
    if (threadIdx.x < 128) {
        atomicAdd(&bnS[threadIdx.x], ldsS[threadIdx.x]);
        atomicAdd(&bnQ[threadIdx.x], ldsQ[threadIdx.x]);
    }
}

// ---- final epilogue, float4 ----
__global__ __launch_bounds__(256) void k_final(const float* __restrict__ y3,
                                               const float* __restrict__ x,
                                               const float* __restrict__ c2,
                                               const float* __restrict__ bnS,
                                               const float* __restrict__ bnQ,
                                               const float* __restrict__ bng,
                                               const float* __restrict__ bnb,
                                               const float* __restrict__ b2v,
                                               const float* __restrict__ pa,
                                               const float* __restrict__ b3v,
                                               float* __restrict__ out) {
    const int idx4 = blockIdx.x * 256 + threadIdx.x;   // < 1,048,576
    const int hw = (idx4 & 1023) * 4;
    const int cb = idx4 >> 10;
    const int co = cb & 127;
    const int n = cb >> 7;
    const float mu = bnS[co] * (1.f / 32768.f);
    const float var = bnQ[co] * (1.f / 32768.f) - mu * mu;
    const float rstd = rsqrtf(var + EPS_);
    const float gm = rstd * bng[co];
    const float bt = bnb[co] - mu * gm;
    const size_t obase = (((size_t)(n * C_ + co)) << 12) + hw;
    float4 v = *(const float4*)(y3 + obase);
    v.x = v.x * gm + bt; v.y = v.y * gm + bt; v.z = v.z * gm + bt; v.w = v.w * gm + bt;

    const int ch0 = 2 * co;
    float4 pA, pB;
    if (co < 64) {
        pA = *(const float4*)(x + (((size_t)(n * C_ + ch0)) << 12) + hw);
        pB = *(const float4*)(x + (((size_t)(n * C_ + ch0 + 1)) << 12) + hw);
    } else {
        int d = ch0 - 128;
        pA = *(const float4*)(c2 + (((size_t)(n * C_ + d)) << 12) + hw);
        pB = *(const float4*)(c2 + (((size_t)(n * C_ + d + 1)) << 12) + hw);
    }
    const float bias2 = b2v[n * 128 + co];
    const float aP = pa[co];
    const float bias3 = b3v[n * 128 + co];
    float4 r;
    float t;
    t = v.x + 0.5f * (pA.x + pB.x) + bias2; t = (t >= 0.f) ? t : aP * t; r.x = t + bias3;
    t = v.y + 0.5f * (pA.y + pB.y) + bias2; t = (t >= 0.f) ? t : aP * t; r.y = t + bias3;
    t = v.z + 0.5f * (pA.z + pB.z) + bias2; t = (t >= 0.f) ? t : aP * t; r.z = t + bias3;
    t = v.w + 0.5f * (pA.w + pB.w) + bias2; t = (t >= 0.f) ? t : aP * t; r.w = t + bias3;
    *(float4*)(out + obase) = r;
}

// ---------------- launch ----------------
extern "C" void kernel_launch(void* const* d_in, const int* in_sizes, int n_in,
                              void* d_out, int out_size, void* d_ws, size_t ws_size,
                              hipStream_t stream) {
    const float* c       = (const float*)d_in[0];
    const float* x       = (const float*)d_in[1];
    const float* emb     = (const float*)d_in[2];
    const float* gn1_g   = (const float*)d_in[3];
    const float* gn1_b   = (const float*)d_in[4];
    const float* conv1_w = (const float*)d_in[5];
    const float* conv1_b = (const float*)d_in[6];
    const float* emb_w   = (const float*)d_in[7];
    const float* emb_b   = (const float*)d_in[8];
    const float* gn2_g   = (const float*)d_in[9];
    const float* gn2_b   = (const float*)d_in[10];
    const float* conv2_w = (const float*)d_in[11];
    const float* conv2_b = (const float*)d_in[12];
    const float* m1_w    = (const float*)d_in[13];
    const float* m1_b    = (const float*)d_in[14];
    const float* bconv_w = (const float*)d_in[15];
    const float* bconv_b = (const float*)d_in[16];
    const float* bn_g    = (const float*)d_in[17];
    const float* bn_b    = (const float*)d_in[18];
    const float* m2_w    = (const float*)d_in[19];
    const float* m2_b    = (const float*)d_in[20];
    const float* prelu_a = (const float*)d_in[21];
    const float* m3_w    = (const float*)d_in[22];
    const float* m3_b    = (const float*)d_in[23];
    float* out = (float*)d_out;

    // ws (~41.2 MB): a_buf 16MB | y_buf 16MB | actA(bf16)/S(i8) aliased 8MB |
    //                sgn 288KB | Wc1 288KB | Wc2 288KB | small vecs
    float* ws = (float*)d_ws;
    const size_t NCHW = (size_t)B_ * C_ * HW_;       // 4,194,304
    float*  a_buf = ws;
    float*  y_buf = ws + NCHW;
    unsigned short* actA = (unsigned short*)(ws + 2 * NCHW);   // 8 MB (NHWC bf16)
    int8_t* S     = (int8_t*)(ws + 2 * NCHW);                  // aliases actA
    int8_t* sgn   = (int8_t*)(ws + 2 * NCHW + NCHW / 2);       // 294912 B
    unsigned short* Wc1 = (unsigned short*)(ws + 2 * NCHW + NCHW / 2 + 73728);
    unsigned short* Wc2 = Wc1 + C_ * C_ * 9;                   // each 294912 B
    float*  alpha = ws + 2 * NCHW + NCHW / 2 + 73728 + 2 * 73728;
    float*  eo    = alpha + 128;
    float*  b1v   = eo + B_ * 256;
    float*  b2v   = b1v + B_ * 256;
    float*  b3v   = b2v + B_ * 128;
    float*  bnS   = b3v + B_ * 128;
    float*  bnQ   = bnS + 128;

    k_prep<<<704, 256, 0, stream>>>(bconv_w, sgn, alpha, bnS, bnQ,
                                    conv1_w, conv2_w, Wc1, Wc2);
    k_emb2<<<192, 256, 0, stream>>>(emb, emb_w, emb_b, m1_w, m1_b, m2_w, m2_b,
                                    m3_w, m3_b, eo, b1v, b2v, b3v);
    k_gn1t<<<B_ * 32, 1024, 0, stream>>>(c, gn1_g, gn1_b, actA);
    k_convm<false><<<dim3(64, B_), 256, 0, stream>>>(actA, Wc1, conv1_b, nullptr, y_buf);
    k_gn2t<<<B_ * 32, 1024, 0, stream>>>(y_buf, gn2_g, gn2_b, eo, actA);
    k_convm<true><<<dim3(64, B_), 256, 0, stream>>>(actA, Wc2, conv2_b, c, a_buf); // a_buf = c2
    k_sign_t<<<dim3(64, B_), 256, 0, stream>>>(x, a_buf, b1v, S);                  // S overwrites actA
    k_bconv<<<dim3(64, B_), 256, 0, stream>>>(S, sgn, alpha, bconv_b, y_buf, bnS, bnQ); // y_buf = y3
    k_final<<<NCHW / 1024, 256, 0, stream>>>(y_buf, x, a_buf, bnS, bnQ, bn_g, bn_b,
                                             b2v, prelu_a, b3v, out);
}

// Round 9
// 255.390 us; speedup vs baseline: 4.6319x; 1.0420x over previous
//
#include <hip/hip_runtime.h>
#include <stdint.h>

// ConcatLayer_55654186221983 on MI355X (gfx950). All fp32 I/O.
// B=8, C=128, C2=256, H=W=64, EMB=512, GROUPS=32, EPS=1e-5.
// R9: GN2 stats fused into conv1 epilogue; sign+transpose fused into conv2
//     epilogue (kills k_sign_t); prep+emb merged. 9 -> 7 dispatches.

#define B_   8
#define C_   128
#define C2_  256
#define HW_  4096
#define EMB_ 512
#define EPS_ 1e-5f

typedef int   v16i __attribute__((ext_vector_type(16)));
typedef float v16f __attribute__((ext_vector_type(16)));
typedef short v8s  __attribute__((ext_vector_type(8)));
typedef int   v4i  __attribute__((ext_vector_type(4)));

// LDS tile: 3 rows x 66 cols x (256 data + 16 pad) bytes
#define COLB 272
#define LDSZ (3 * 66 * COLB)

__device__ __forceinline__ float silu(float v) { return v / (1.f + expf(-v)); }
__device__ __forceinline__ unsigned short f2bf(float f) {
    unsigned int x = __float_as_uint(f);
    return (unsigned short)((x + 0x7FFFu + ((x >> 16) & 1u)) >> 16);  // RNE
}
__device__ __forceinline__ int8_t sgn8(float v) {
    return (v > 0.f) ? (int8_t)1 : ((v < 0.f) ? (int8_t)(-1) : (int8_t)0);
}

// ---- merged prep + embedding:
// blocks 0..127: binary weights + alpha + zero bnS/bnQ/gnS/gnQ
// blocks 128..703: conv weight relayout
// blocks 704..895: embedding MLPs (wave per output row)
__global__ __launch_bounds__(256) void k_prep(
    const float* __restrict__ w, int8_t* __restrict__ sgn,
    float* __restrict__ alpha, float* __restrict__ bnS, float* __restrict__ bnQ,
    float* __restrict__ gnS, float* __restrict__ gnQ,
    const float* __restrict__ w1, const float* __restrict__ w2,
    unsigned short* __restrict__ Wc1, unsigned short* __restrict__ Wc2,
    const float* __restrict__ emb,
    const float* __restrict__ ew, const float* __restrict__ ebb,
    const float* __restrict__ m1w, const float* __restrict__ m1b,
    const float* __restrict__ m2w, const float* __restrict__ m2b,
    const float* __restrict__ m3w, const float* __restrict__ m3b,
    float* __restrict__ eo, float* __restrict__ b1,
    float* __restrict__ b2, float* __restrict__ b3) {
    __shared__ float red[256];
    const int blk = blockIdx.x, tid = threadIdx.x;
    if (blk < 128) {
        const int o = blk;
        if (o == 0 && tid < 128) { bnS[tid] = 0.f; bnQ[tid] = 0.f; }
        if (o == 1) { gnS[tid] = 0.f; }           // 256 floats
        if (o == 2) { gnQ[tid] = 0.f; }
        const float* wr = w + (size_t)o * (C2_ * 9);
        float s = 0.f;
        for (int i = tid; i < C2_ * 9; i += 256) s += fabsf(wr[i]);
        red[tid] = s;
        __syncthreads();
        for (int st = 128; st > 0; st >>= 1) {
            if (tid < st) red[tid] += red[tid + st];
            __syncthreads();
        }
        if (tid == 0) alpha[o] = red[0] / (float)(C2_ * 9);
        for (int kk = 0; kk < 9; ++kk) {
            float v = wr[tid * 9 + kk];   // tid == ci
            sgn[((size_t)(kk * 16 + (tid >> 4)) * C_ + o) * 16 + (tid & 15)] = sgn8(v);
        }
    } else if (blk < 704) {
        int i = (blk - 128) * 256 + tid;
        int co = i / (C_ * 9);
        int rem = i - co * (C_ * 9);
        int ci = rem / 9, kk = rem - ci * 9;
        size_t d = ((size_t)(kk * 16 + (ci >> 3)) * C_ + co) * 8 + (ci & 7);
        Wc1[d] = f2bf(w1[i]);
        Wc2[d] = f2bf(w2[i]);
    } else {
        const int o = (blk - 704) * 4 + (tid >> 6);   // wave-uniform, 0..767
        const int l = tid & 63;
        const float* wv;
        float bias;
        float* dst;
        int dstride;
        if (o < 256)      { wv = ew  + (size_t)o * EMB_;              bias = ebb[o];    dst = eo + o;  dstride = 256; }
        else if (o < 512) { int r = o - 256; wv = m1w + (size_t)r * EMB_; bias = m1b[r]; dst = b1 + r; dstride = 256; }
        else if (o < 640) { int r = o - 512; wv = m2w + (size_t)r * EMB_; bias = m2b[r]; dst = b2 + r; dstride = 128; }
        else              { int r = o - 640; wv = m3w + (size_t)r * EMB_; bias = m3b[r]; dst = b3 + r; dstride = 128; }
        const float4 wa = *(const float4*)(wv + 8 * l);
        const float4 wb = *(const float4*)(wv + 8 * l + 4);
#pragma unroll
        for (int b = 0; b < B_; ++b) {
            const float* s = emb + b * EMB_ + 8 * l;
            float4 sa = *(const float4*)(s);
            float4 sb = *(const float4*)(s + 4);
            float p = wa.x * silu(sa.x) + wa.y * silu(sa.y) + wa.z * silu(sa.z) + wa.w * silu(sa.w) +
                      wb.x * silu(sb.x) + wb.y * silu(sb.y) + wb.z * silu(sb.z) + wb.w * silu(sb.w);
#pragma unroll
            for (int off = 32; off > 0; off >>= 1) p += __shfl_down(p, off, 64);
            if (l == 0) dst[b * dstride] = bias + p;
        }
    }
}

// ---- GN1 + SiLU: NCHW fp32 in -> NHWC bf16 out (1024 threads) ----
__global__ __launch_bounds__(1024) void k_gn1t(const float* __restrict__ in,
                                               const float* __restrict__ g,
                                               const float* __restrict__ b,
                                               unsigned short* __restrict__ act) {
    __shared__ float ssum[1024], ssq[1024];
    __shared__ float s_mu, s_rstd;
    const int tid = threadIdx.x;
    const int n = blockIdx.x >> 5, grp = blockIdx.x & 31;
    const size_t base = ((size_t)(n * C_ + grp * 4)) << 12;
    float sum = 0.f, sq = 0.f;
    const float4* in4 = (const float4*)(in + base);
    for (int i = tid; i < 4096; i += 1024) {
        float4 v = in4[i];
        sum += v.x + v.y + v.z + v.w;
        sq += v.x * v.x + v.y * v.y + v.z * v.z + v.w * v.w;
    }
    ssum[tid] = sum; ssq[tid] = sq;
    __syncthreads();
    for (int st = 512; st > 0; st >>= 1) {
        if (tid < st) { ssum[tid] += ssum[tid + st]; ssq[tid] += ssq[tid + st]; }
        __syncthreads();
    }
    if (tid == 0) {
        float mu = ssum[0] * (1.f / 16384.f);
        float var = ssq[0] * (1.f / 16384.f) - mu * mu;
        s_mu = mu; s_rstd = rsqrtf(var + EPS_);
    }
    __syncthreads();
    const float mu = s_mu, rstd = s_rstd;
    float gg[4], bb[4];
#pragma unroll
    for (int j = 0; j < 4; ++j) { gg[j] = g[grp * 4 + j]; bb[j] = b[grp * 4 + j]; }
    for (int hw = tid; hw < HW_; hw += 1024) {
        union { unsigned short u[4]; uint2 v; } pk;
#pragma unroll
        for (int j = 0; j < 4; ++j) {
            float v = in[base + ((size_t)j << 12) + hw];
            pk.u[j] = f2bf(silu((v - mu) * rstd * gg[j] + bb[j]));
        }
        *(uint2*)(act + ((size_t)(n * HW_ + hw)) * C_ + grp * 4) = pk.v;
    }
}

// ---- GN2 apply-only (+FiLM+SiLU): stats precomputed by conv1 epilogue ----
__global__ __launch_bounds__(1024) void k_gn2a(const float* __restrict__ in,
                                               const float* __restrict__ g,
                                               const float* __restrict__ b,
                                               const float* __restrict__ eo,
                                               const float* __restrict__ gnS,
                                               const float* __restrict__ gnQ,
                                               unsigned short* __restrict__ act) {
    const int tid = threadIdx.x;
    const int n = blockIdx.x >> 5, grp = blockIdx.x & 31;
    const size_t base = ((size_t)(n * C_ + grp * 4)) << 12;
    const float mu = gnS[n * 32 + grp] * (1.f / 16384.f);
    const float var = gnQ[n * 32 + grp] * (1.f / 16384.f) - mu * mu;
    const float rstd = rsqrtf(var + EPS_);
    float sc[4], sh[4], gg[4], bb[4];
#pragma unroll
    for (int j = 0; j < 4; ++j) {
        int ch = grp * 4 + j;
        gg[j] = g[ch]; bb[j] = b[ch];
        sc[j] = 1.f + eo[n * 256 + ch];
        sh[j] = eo[n * 256 + 128 + ch];
    }
    for (int hw = tid; hw < HW_; hw += 1024) {
        union { unsigned short u[4]; uint2 v; } pk;
#pragma unroll
        for (int j = 0; j < 4; ++j) {
            float v = in[base + ((size_t)j << 12) + hw];
            float y = ((v - mu) * rstd * gg[j] + bb[j]) * sc[j] + sh[j];
            pk.u[j] = f2bf(silu(y));
        }
        *(uint2*)(act + ((size_t)(n * HW_ + hw)) * C_ + grp * 4) = pk.v;
    }
}

// ---- shared LDS row-staging: 3 rows x 64 cols of 256B -> padded cols 1..64 ----
__device__ __forceinline__ void stage_rows(char* lds, const char* rs0,
                                           const char* rs1, const char* rs2) {
    const int tid = threadIdx.x;
    const char* rs[3] = {rs0, rs1, rs2};
    if (tid < 96) {
        int r = tid / 32, q = tid & 31;
        int c = (q >> 4) ? 65 : 0, o = q & 15;
        *(float4*)(lds + (r * 66 + c) * COLB + o * 16) = make_float4(0.f, 0.f, 0.f, 0.f);
    }
#pragma unroll
    for (int u = 0; u < 12; ++u) {
        int idx = u * 256 + tid;
        int r = idx >> 10, rem = idx & 1023;
        int x = rem >> 4, o = rem & 15;
        char* dst = lds + (r * 66 + x + 1) * COLB + o * 16;
        if (rs[r]) *(float4*)dst = *(const float4*)(rs[r] + x * 256 + o * 16);
        else       *(float4*)dst = make_float4(0.f, 0.f, 0.f, 0.f);
    }
}

// ---- conv1: bf16 MFMA implicit-GEMM + fused GN2 stats ----
__global__ __launch_bounds__(256) void k_conv1(const unsigned short* __restrict__ act,
                                               const unsigned short* __restrict__ Wc,
                                               const float* __restrict__ bias,
                                               float* __restrict__ out,
                                               float* __restrict__ gnS,
                                               float* __restrict__ gnQ) {
    __shared__ __align__(16) char lds[LDSZ];
    const int y = blockIdx.x;
    const int n = blockIdx.y;
    const char* base = (const char*)(act + ((size_t)n * 64) * 64 * C_);
    stage_rows(lds,
               (y > 0)  ? base + (size_t)(y - 1) * 16384 : nullptr,
               base + (size_t)y * 16384,
               (y < 63) ? base + (size_t)(y + 1) * 16384 : nullptr);
    __syncthreads();

    const int w = threadIdx.x >> 6;
    const int l = threadIdx.x & 63;
    const int lm = l & 31;
    const int lh = l >> 5;

    v16f acc0, acc1;
#pragma unroll
    for (int i = 0; i < 16; ++i) { acc0[i] = 0.f; acc1[i] = 0.f; }

#pragma unroll
    for (int kk = 0; kk < 9; ++kk) {
        const int r = kk / 3, dx = kk % 3 - 1;
        const char* col0 = lds + (r * 66 + lm + 1 + dx) * COLB + 16 * lh;
        const char* col1 = col0 + 32 * COLB;
        const unsigned short* wbase = Wc + (size_t)(kk * 16 + lh) * C_ * 8 + (32 * w + lm) * 8;
#pragma unroll
        for (int cb = 0; cb < 8; ++cb) {
            v8s a = *(const v8s*)(wbase + (size_t)(2 * cb) * C_ * 8);
            v8s b0 = *(const v8s*)(col0 + 32 * cb);
            v8s b1 = *(const v8s*)(col1 + 32 * cb);
            acc0 = __builtin_amdgcn_mfma_f32_32x32x16_bf16(a, b0, acc0, 0, 0, 0);
            acc1 = __builtin_amdgcn_mfma_f32_32x32x16_bf16(a, b1, acc1, 0, 0, 0);
        }
    }
    float pr[16], qr[16];
#pragma unroll
    for (int r = 0; r < 16; ++r) {
        const int row = (r & 3) + 8 * (r >> 2) + 4 * lh;
        const int co = 32 * w + row;
        const float bv = bias[co];
        const size_t o = (((size_t)n * C_ + co) << 12) + (y << 6);
        float v0 = acc0[r] + bv, v1 = acc1[r] + bv;
        out[o + lm] = v0;
        out[o + 32 + lm] = v1;
        pr[r] = v0 + v1;
        qr[r] = v0 * v0 + v1 * v1;
    }
    // fused GN2 stats: per-channel partials -> per-group atomics
    __syncthreads();
    float* ldsS = (float*)lds;
    float* ldsQ = (float*)lds + 128;
#pragma unroll
    for (int r = 0; r < 16; ++r) {
        float p = pr[r], q = qr[r];
#pragma unroll
        for (int m = 16; m > 0; m >>= 1) {
            p += __shfl_xor(p, m, 64);
            q += __shfl_xor(q, m, 64);
        }
        if (lm == 0) {
            const int row = (r & 3) + 8 * (r >> 2) + 4 * lh;
            const int co = 32 * w + row;
            ldsS[co] = p;
            ldsQ[co] = q;
        }
    }
    __syncthreads();
    if (threadIdx.x < 32) {
        const int g = threadIdx.x;
        float p = ldsS[4 * g] + ldsS[4 * g + 1] + ldsS[4 * g + 2] + ldsS[4 * g + 3];
        float q = ldsQ[4 * g] + ldsQ[4 * g + 1] + ldsQ[4 * g + 2] + ldsQ[4 * g + 3];
        atomicAdd(&gnS[n * 32 + g], p);
        atomicAdd(&gnQ[n * 32 + g], q);
    }
}

// ---- conv2: bf16 MFMA + residual + fused sign+transpose (writes c2 and S) ----
__global__ __launch_bounds__(256) void k_conv2(const unsigned short* __restrict__ act,
                                               const unsigned short* __restrict__ Wc,
                                               const float* __restrict__ bias,
                                               const float* __restrict__ res,
                                               const float* __restrict__ xin,
                                               const float* __restrict__ b1v,
                                               float* __restrict__ out,
                                               int8_t* __restrict__ S) {
    __shared__ __align__(16) char lds[LDSZ];
    const int y = blockIdx.x;
    const int n = blockIdx.y;
    const char* base = (const char*)(act + ((size_t)n * 64) * 64 * C_);
    stage_rows(lds,
               (y > 0)  ? base + (size_t)(y - 1) * 16384 : nullptr,
               base + (size_t)y * 16384,
               (y < 63) ? base + (size_t)(y + 1) * 16384 : nullptr);
    __syncthreads();

    const int w = threadIdx.x >> 6;
    const int l = threadIdx.x & 63;
    const int lm = l & 31;
    const int lh = l >> 5;

    v16f acc0, acc1;
#pragma unroll
    for (int i = 0; i < 16; ++i) { acc0[i] = 0.f; acc1[i] = 0.f; }

#pragma unroll
    for (int kk = 0; kk < 9; ++kk) {
        const int r = kk / 3, dx = kk % 3 - 1;
        const char* col0 = lds + (r * 66 + lm + 1 + dx) * COLB + 16 * lh;
        const char* col1 = col0 + 32 * COLB;
        const unsigned short* wbase = Wc + (size_t)(kk * 16 + lh) * C_ * 8 + (32 * w + lm) * 8;
#pragma unroll
        for (int cb = 0; cb < 8; ++cb) {
            v8s a = *(const v8s*)(wbase + (size_t)(2 * cb) * C_ * 8);
            v8s b0 = *(const v8s*)(col0 + 32 * cb);
            v8s b1 = *(const v8s*)(col1 + 32 * cb);
            acc0 = __builtin_amdgcn_mfma_f32_32x32x16_bf16(a, b0, acc0, 0, 0, 0);
            acc1 = __builtin_amdgcn_mfma_f32_32x32x16_bf16(a, b1, acc1, 0, 0, 0);
        }
    }
    float c2v0[16], c2v1[16];
#pragma unroll
    for (int r = 0; r < 16; ++r) {
        const int row = (r & 3) + 8 * (r >> 2) + 4 * lh;
        const int co = 32 * w + row;
        const float bv = bias[co];
        const size_t o = (((size_t)n * C_ + co) << 12) + (y << 6);
        float v0 = acc0[r] + bv + res[o + lm];
        float v1 = acc1[r] + bv + res[o + 32 + lm];
        out[o + lm] = v0;
        out[o + 32 + lm] = v1;
        c2v0[r] = v0;
        c2v1[r] = v1;
    }

    // ---- fused sign: build S row [64 px][256 ch] bytes in LDS, then store ----
    __syncthreads();                 // staging LDS fully consumed
    // c2 half: pack 4 consecutive channels per u32 (rows r&3 are consecutive)
#pragma unroll
    for (int q = 0; q < 4; ++q) {
        const int co0 = 32 * w + 8 * q + 4 * lh;
        const float b0 = b1v[n * 256 + 128 + co0];
        const float b1b = b1v[n * 256 + 128 + co0 + 1];
        const float b2b = b1v[n * 256 + 128 + co0 + 2];
        const float b3b = b1v[n * 256 + 128 + co0 + 3];
        union { int8_t b[4]; int u; } p0, p1;
        p0.b[0] = sgn8(c2v0[4 * q] + b0);  p1.b[0] = sgn8(c2v1[4 * q] + b0);
        p0.b[1] = sgn8(c2v0[4 * q + 1] + b1b); p1.b[1] = sgn8(c2v1[4 * q + 1] + b1b);
        p0.b[2] = sgn8(c2v0[4 * q + 2] + b2b); p1.b[2] = sgn8(c2v1[4 * q + 2] + b2b);
        p0.b[3] = sgn8(c2v0[4 * q + 3] + b3b); p1.b[3] = sgn8(c2v1[4 * q + 3] + b3b);
        *(int*)(lds + lm * COLB + 128 + co0) = p0.u;
        *(int*)(lds + (32 + lm) * COLB + 128 + co0) = p1.u;
    }
    // x half: 128 ch x 16 float4-segments
#pragma unroll
    for (int u = 0; u < 8; ++u) {
        int idx = u * 256 + threadIdx.x;
        int ch = idx >> 4, seg = idx & 15;
        float4 v = *(const float4*)(xin + (((size_t)(n * C_ + ch)) << 12) + (y << 6) + 4 * seg);
        const float bv = b1v[n * 256 + ch];
        lds[(4 * seg) * COLB + ch]     = sgn8(v.x + bv);
        lds[(4 * seg + 1) * COLB + ch] = sgn8(v.y + bv);
        lds[(4 * seg + 2) * COLB + ch] = sgn8(v.z + bv);
        lds[(4 * seg + 3) * COLB + ch] = sgn8(v.w + bv);
    }
    __syncthreads();
    int8_t* Srow = S + ((size_t)(n * HW_) + (y << 6)) * C2_;
#pragma unroll
    for (int u = 0; u < 4; ++u) {
        int idx = u * 256 + threadIdx.x;
        int px = idx >> 4, c16 = idx & 15;
        *(int4*)(Srow + (size_t)px * C2_ + 16 * c16) = *(const int4*)(lds + px * COLB + 16 * c16);
    }
}

// ---- binary conv: i8 K=32 MFMA implicit GEMM + fused BN stats ----
__global__ __launch_bounds__(256) void k_bconv(const int8_t* __restrict__ S,
                                               const int8_t* __restrict__ Wk,
                                               const float* __restrict__ alpha,
                                               const float* __restrict__ bias,
                                               float* __restrict__ out,
                                               float* __restrict__ bnS,
                                               float* __restrict__ bnQ) {
    __shared__ __align__(16) char lds[LDSZ];
    const int y = blockIdx.x;
    const int n = blockIdx.y;
    const char* base = (const char*)(S + ((size_t)n * 64) * 64 * C2_);
    stage_rows(lds,
               (y > 0)  ? base + (size_t)(y - 1) * 16384 : nullptr,
               base + (size_t)y * 16384,
               (y < 63) ? base + (size_t)(y + 1) * 16384 : nullptr);
    __syncthreads();

    const int w = threadIdx.x >> 6;
    const int l = threadIdx.x & 63;
    const int lm = l & 31;
    const int lh = l >> 5;

    v16i acc0, acc1;
#pragma unroll
    for (int i = 0; i < 16; ++i) { acc0[i] = 0; acc1[i] = 0; }

#pragma unroll
    for (int kk = 0; kk < 9; ++kk) {
        const int r = kk / 3, dx = kk % 3 - 1;
        const char* col0 = lds + (r * 66 + lm + 1 + dx) * COLB + 16 * lh;
        const char* col1 = col0 + 32 * COLB;
        const int8_t* wbase = Wk + (size_t)(kk * 16 + lh) * C_ * 16 + (32 * w + lm) * 16;
#pragma unroll
        for (int s = 0; s < 8; ++s) {
            v4i a = *(const v4i*)(wbase + (size_t)(2 * s) * C_ * 16);
            v4i b0 = *(const v4i*)(col0 + 32 * s);
            v4i b1 = *(const v4i*)(col1 + 32 * s);
            acc0 = __builtin_amdgcn_mfma_i32_32x32x32_i8(a, b0, acc0, 0, 0, 0);
            acc1 = __builtin_amdgcn_mfma_i32_32x32x32_i8(a, b1, acc1, 0, 0, 0);
        }
    }

    float pr[16], qr[16];
#pragma unroll
    for (int r = 0; r < 16; ++r) {
        const int row = (r & 3) + 8 * (r >> 2) + 4 * lh;
        const int co = 32 * w + row;
        const float av = alpha[co], bv = bias[co];
        const size_t o = (((size_t)n * C_ + co) << 12) + (y << 6);
        float v0 = av * (float)acc0[r] + bv;
        float v1 = av * (float)acc1[r] + bv;
        out[o + lm]      = v0;
        out[o + 32 + lm] = v1;
        pr[r] = v0 + v1;
        qr[r] = v0 * v0 + v1 * v1;
    }
    __syncthreads();
    float* ldsS = (float*)lds;
    float* ldsQ = (float*)lds + 128;
#pragma unroll
    for (int r = 0; r < 16; ++r) {
        float p = pr[r], q = qr[r];
#pragma unroll
        for (int m = 16; m > 0; m >>= 1) {
            p += __shfl_xor(p, m, 64);
            q += __shfl_xor(q, m, 64);
        }
        if (lm == 0) {
            const int row = (r & 3) + 8 * (r >> 2) + 4 * lh;
            const int co = 32 * w + row;
            ldsS[co] = p;
            ldsQ[co] = q;
        }
    }
    __syncthreads();
    if (threadIdx.x < 128) {
        atomicAdd(&bnS[threadIdx.x], ldsS[threadIdx.x]);
        atomicAdd(&bnQ[threadIdx.x], ldsQ[threadIdx.x]);
    }
}

// ---- final epilogue, float4 ----
__global__ __launch_bounds__(256) void k_final(const float* __restrict__ y3,
                                               const float* __restrict__ x,
                                               const float* __restrict__ c2,
                                               const float* __restrict__ bnS,
                                               const float* __restrict__ bnQ,
                                               const float* __restrict__ bng,
                                               const float* __restrict__ bnb,
                                               const float* __restrict__ b2v,
                                               const float* __restrict__ pa,
                                               const float* __restrict__ b3v,
                                               float* __restrict__ out) {
    const int idx4 = blockIdx.x * 256 + threadIdx.x;   // < 1,048,576
    const int hw = (idx4 & 1023) * 4;
    const int cb = idx4 >> 10;
    const int co = cb & 127;
    const int n = cb >> 7;
    const float mu = bnS[co] * (1.f / 32768.f);
    const float var = bnQ[co] * (1.f / 32768.f) - mu * mu;
    const float rstd = rsqrtf(var + EPS_);
    const float gm = rstd * bng[co];
    const float bt = bnb[co] - mu * gm;
    const size_t obase = (((size_t)(n * C_ + co)) << 12) + hw;
    float4 v = *(const float4*)(y3 + obase);
    v.x = v.x * gm + bt; v.y = v.y * gm + bt; v.z = v.z * gm + bt; v.w = v.w * gm + bt;

    const int ch0 = 2 * co;
    float4 pA, pB;
    if (co < 64) {
        pA = *(const float4*)(x + (((size_t)(n * C_ + ch0)) << 12) + hw);
        pB = *(const float4*)(x + (((size_t)(n * C_ + ch0 + 1)) << 12) + hw);
    } else {
        int d = ch0 - 128;
        pA = *(const float4*)(c2 + (((size_t)(n * C_ + d)) << 12) + hw);
        pB = *(const float4*)(c2 + (((size_t)(n * C_ + d + 1)) << 12) + hw);
    }
    const float bias2 = b2v[n * 128 + co];
    const float aP = pa[co];
    const float bias3 = b3v[n * 128 + co];
    float4 r;
    float t;
    t = v.x + 0.5f * (pA.x + pB.x) + bias2; t = (t >= 0.f) ? t : aP * t; r.x = t + bias3;
    t = v.y + 0.5f * (pA.y + pB.y) + bias2; t = (t >= 0.f) ? t : aP * t; r.y = t + bias3;
    t = v.z + 0.5f * (pA.z + pB.z) + bias2; t = (t >= 0.f) ? t : aP * t; r.z = t + bias3;
    t = v.w + 0.5f * (pA.w + pB.w) + bias2; t = (t >= 0.f) ? t : aP * t; r.w = t + bias3;
    *(float4*)(out + obase) = r;
}

// ---------------- launch ----------------
extern "C" void kernel_launch(void* const* d_in, const int* in_sizes, int n_in,
                              void* d_out, int out_size, void* d_ws, size_t ws_size,
                              hipStream_t stream) {
    const float* c       = (const float*)d_in[0];
    const float* x       = (const float*)d_in[1];
    const float* emb     = (const float*)d_in[2];
    const float* gn1_g   = (const float*)d_in[3];
    const float* gn1_b   = (const float*)d_in[4];
    const float* conv1_w = (const float*)d_in[5];
    const float* conv1_b = (const float*)d_in[6];
    const float* emb_w   = (const float*)d_in[7];
    const float* emb_b   = (const float*)d_in[8];
    const float* gn2_g   = (const float*)d_in[9];
    const float* gn2_b   = (const float*)d_in[10];
    const float* conv2_w = (const float*)d_in[11];
    const float* conv2_b = (const float*)d_in[12];
    const float* m1_w    = (const float*)d_in[13];
    const float* m1_b    = (const float*)d_in[14];
    const float* bconv_w = (const float*)d_in[15];
    const float* bconv_b = (const float*)d_in[16];
    const float* bn_g    = (const float*)d_in[17];
    const float* bn_b    = (const float*)d_in[18];
    const float* m2_w    = (const float*)d_in[19];
    const float* m2_b    = (const float*)d_in[20];
    const float* prelu_a = (const float*)d_in[21];
    const float* m3_w    = (const float*)d_in[22];
    const float* m3_b    = (const float*)d_in[23];
    float* out = (float*)d_out;

    // ws (~41.2 MB): a_buf 16MB | y_buf 16MB | actA(bf16)/S(i8) aliased 8MB |
    //                sgn 288KB | Wc1 288KB | Wc2 288KB | small vecs
    float* ws = (float*)d_ws;
    const size_t NCHW = (size_t)B_ * C_ * HW_;       // 4,194,304
    float*  a_buf = ws;
    float*  y_buf = ws + NCHW;
    unsigned short* actA = (unsigned short*)(ws + 2 * NCHW);   // 8 MB (NHWC bf16)
    int8_t* S     = (int8_t*)(ws + 2 * NCHW);                  // aliases actA
    int8_t* sgn   = (int8_t*)(ws + 2 * NCHW + NCHW / 2);       // 294912 B
    unsigned short* Wc1 = (unsigned short*)(ws + 2 * NCHW + NCHW / 2 + 73728);
    unsigned short* Wc2 = Wc1 + C_ * C_ * 9;                   // each 294912 B
    float*  alpha = ws + 2 * NCHW + NCHW / 2 + 73728 + 2 * 73728;
    float*  eo    = alpha + 128;
    float*  b1v   = eo + B_ * 256;
    float*  b2v   = b1v + B_ * 256;
    float*  b3v   = b2v + B_ * 128;
    float*  bnS   = b3v + B_ * 128;
    float*  bnQ   = bnS + 128;
    float*  gnS   = bnQ + 128;   // 256
    float*  gnQ   = gnS + 256;   // 256

    k_prep<<<896, 256, 0, stream>>>(bconv_w, sgn, alpha, bnS, bnQ, gnS, gnQ,
                                    conv1_w, conv2_w, Wc1, Wc2,
                                    emb, emb_w, emb_b, m1_w, m1_b, m2_w, m2_b,
                                    m3_w, m3_b, eo, b1v, b2v, b3v);
    k_gn1t<<<B_ * 32, 1024, 0, stream>>>(c, gn1_g, gn1_b, actA);
    k_conv1<<<dim3(64, B_), 256, 0, stream>>>(actA, Wc1, conv1_b, y_buf, gnS, gnQ);
    k_gn2a<<<B_ * 32, 1024, 0, stream>>>(y_buf, gn2_g, gn2_b, eo, gnS, gnQ, actA);
    k_conv2<<<dim3(64, B_), 256, 0, stream>>>(actA, Wc2, conv2_b, c, x, b1v, a_buf, S); // a_buf = c2
    k_bconv<<<dim3(64, B_), 256, 0, stream>>>(S, sgn, alpha, bconv_b, y_buf, bnS, bnQ); // y_buf = y3
    k_final<<<NCHW / 1024, 256, 0, stream>>>(y_buf, x, a_buf, bnS, bnQ, bn_g, bn_b,
                                             b2v, prelu_a, b3v, out);
}